// Round 4
// baseline (1467.280 us; speedup 1.0000x reference)
//
#include <hip/hip_runtime.h>

// ---------------------------------------------------------------------------
// SAM windowed-attention block, bf16-MFMA implementation.
// B=8 H=W=64 DIM=768 NH=12 HD=64 WS=14 N=196 PAD=6 -> 70x70, 5x5=25 windows,
// Bp=200 windows, 2400 (window,head) pairs. All GEMMs bf16 MFMA 16x16x32,
// fp32 accumulate. Softmax/LN/gelu in fp32.
// R4: GEMM tile 256x256 (BK=32, 512 thr / 8 waves 2x4, per-wave 128x64,
// acc[8][4]) to double arithmetic intensity (64 -> 128 FLOP per staged byte;
// R3 analysis: 128^2 needs ~100% of a CU's L2-BW share to feed MFMA).
// K-loop schedule is UNCHANGED from R3 (verified): explicit LDS double-buffer
// (2 x 32KB), global_load_lds staging issued before compute, single
// s_waitcnt vmcnt(0) after compute + raw s_barrier, XOR bank swizzle
// (0 conflicts measured), XCD-chunked bijective block swizzle.
// ---------------------------------------------------------------------------

typedef __bf16 bf16x8 __attribute__((ext_vector_type(8)));
typedef float f32x4 __attribute__((ext_vector_type(4)));
typedef unsigned int u32x4 __attribute__((ext_vector_type(4)));

__device__ __forceinline__ unsigned short f2bf(float f) {
  unsigned int u = __builtin_bit_cast(unsigned int, f);
  u += 0x7FFFu + ((u >> 16) & 1u);
  return (unsigned short)(u >> 16);
}

__device__ __forceinline__ bf16x8 ld8(const unsigned short* p) {
  return __builtin_bit_cast(bf16x8, *(const u32x4*)p);
}

// async global->LDS, 16B per lane. LDS dest must be wave-uniform base + lane*16.
__device__ __forceinline__ void gload_lds16(const unsigned short* g,
                                            unsigned short* l) {
  __builtin_amdgcn_global_load_lds(
      (const __attribute__((address_space(1))) unsigned int*)g,
      (__attribute__((address_space(3))) unsigned int*)l, 16, 0, 0);
}

// ---------------------------------------------------------------------------
// Weight transpose fp32[K][N] -> bf16[N][K]  (all dims multiples of 32)
// ---------------------------------------------------------------------------
__global__ void transpose_w(const float* __restrict__ in,
                            unsigned short* __restrict__ out, int K, int N) {
  __shared__ float t[32][33];
  int n = blockIdx.x * 32 + threadIdx.x;
  int kb = blockIdx.y * 32;
#pragma unroll
  for (int i = 0; i < 4; i++) {
    int k = kb + threadIdx.y + i * 8;
    t[threadIdx.y + i * 8][threadIdx.x] = in[(size_t)k * N + n];
  }
  __syncthreads();
  int k2 = kb + threadIdx.x;
#pragma unroll
  for (int i = 0; i < 4; i++) {
    int n2 = blockIdx.x * 32 + threadIdx.y + i * 8;
    out[(size_t)n2 * K + k2] = f2bf(t[threadIdx.x][threadIdx.y + i * 8]);
  }
}

// ---------------------------------------------------------------------------
// Rel-pos tables: Sh[i*14+j] = sum_c rel_h[(i-j+13)*64+c]; same for Sw.
// out layout: [0..195]=Sh, [196..391]=Sw
// ---------------------------------------------------------------------------
__global__ void shsw_kernel(const float* __restrict__ rh,
                            const float* __restrict__ rw,
                            float* __restrict__ o) {
  int t = threadIdx.x;
  if (t < 196) {
    int i = t / 14, j = t % 14, d = i - j + 13;
    float sh = 0.f, sw = 0.f;
    for (int c = 0; c < 64; c++) {
      sh += rh[d * 64 + c];
      sw += rw[d * 64 + c];
    }
    o[t] = sh;
    o[196 + t] = sw;
  }
}

// ---------------------------------------------------------------------------
// LayerNorm over 768. windowed=1: write to window-partitioned layout
// [win*196+t][768]; windowed=0: write [row][768]. Output bf16.
// ---------------------------------------------------------------------------
__global__ __launch_bounds__(256) void ln_kernel(
    const float* __restrict__ xin, const float* __restrict__ w,
    const float* __restrict__ b, unsigned short* __restrict__ out,
    int windowed) {
  __shared__ float red[8];
  __shared__ float ms[2];
  const int tid = threadIdx.x;
  const int blk = blockIdx.x;
  const float* xr = xin + (size_t)blk * 768;
  float v0 = xr[tid], v1 = xr[tid + 256], v2 = xr[tid + 512];
  float s = v0 + v1 + v2;
  float q = v0 * v0 + v1 * v1 + v2 * v2;
#pragma unroll
  for (int off = 32; off > 0; off >>= 1) {
    s += __shfl_down(s, off, 64);
    q += __shfl_down(q, off, 64);
  }
  const int wv = tid >> 6, lane = tid & 63;
  if (lane == 0) { red[wv] = s; red[4 + wv] = q; }
  __syncthreads();
  if (tid == 0) {
    float st = red[0] + red[1] + red[2] + red[3];
    float qt = red[4] + red[5] + red[6] + red[7];
    float mu = st * (1.0f / 768.0f);
    float var = qt * (1.0f / 768.0f) - mu * mu;
    ms[0] = mu;
    ms[1] = rsqrtf(var + 1e-5f);
  }
  __syncthreads();
  float mu = ms[0], sc = ms[1];
  unsigned short* dst;
  if (windowed) {
    int bb = blk >> 12, rem = blk & 4095, h = rem >> 6, ww = rem & 63;
    int win = (bb * 5 + h / 14) * 5 + ww / 14;
    int t = (h % 14) * 14 + (ww % 14);
    dst = out + ((size_t)win * 196 + t) * 768;
  } else {
    dst = out + (size_t)blk * 768;
  }
  dst[tid] = f2bf((v0 - mu) * sc * w[tid] + b[tid]);
  dst[tid + 256] = f2bf((v1 - mu) * sc * w[tid + 256] + b[tid + 256]);
  dst[tid + 512] = f2bf((v2 - mu) * sc * w[tid + 512] + b[tid + 512]);
}

// ---------------------------------------------------------------------------
// bf16 GEMM: C[M][N] = A[M][K] @ Bt[N][K]^T (+ epilogue)
// 256x256 block tile, BK=32, 8 waves in 2x4, each wave 128x64 (8x4 MFMA
// tiles, acc[8][4]). Intensity: 32KB staged per 4.19 MFLOP = 128 FLOP/B
// (2x the 128^2 tile) -> staging needs only ~26 B/cyc/CU of L2 BW.
// Explicit LDS double-buffer (2 x 32KB = 64KB -> 2 blocks/CU): per tile,
// STAGE(next) is issued FIRST (global_load_lds DMA), then ds_read+MFMA on
// current buffer, then one s_waitcnt vmcnt(0) + s_barrier (R3-verified
// 2-phase schedule, unchanged).
// LDS tile layout [256 rows][4 chunks of 16B] (A linear r*64B, B at +16KB),
// swizzled: slot = chunk ^ (row&3) ^ (((row>>2)&1)<<1)  (R3: 0 conflicts).
// DMA dest stays linear (tid*16B); the global SOURCE is inverse-permuted.
// EPI: 0=+bias->bf16 (qkv), 1=+bias+resid, window-unpartition ->fp32 d_out
//      2=+bias,gelu->bf16 (mlp1), 3=+bias, d_out += (mlp2)
// ---------------------------------------------------------------------------
template <int EPI>
__global__ __launch_bounds__(512, 2) void gemm_bt(
    const unsigned short* __restrict__ A, const unsigned short* __restrict__ Bt,
    const float* __restrict__ bias, int M, int N, int K,
    unsigned short* __restrict__ obf, float* __restrict__ of,
    const float* __restrict__ resid) {
  __shared__ __align__(16) unsigned short smem[2][16384];  // [buf][A:16KB|B:16KB]
  const int tid = threadIdx.x;
  const int lane = tid & 63, wv = tid >> 6;
  const int ln15 = lane & 15, quad = lane >> 4;
  const int wm = wv & 1, wn = wv >> 1;  // 2 x 4 wave grid

  // bijective XCD-chunked swizzle (8 XCDs)
  int bid = blockIdx.y * gridDim.x + blockIdx.x;
  {
    const int nwg = gridDim.x * gridDim.y;
    const int qq = nwg >> 3, rr = nwg & 7;
    const int xcd = bid & 7, lo = bid >> 3;
    bid = (xcd < rr ? xcd * (qq + 1) : rr * (qq + 1) + (xcd - rr) * qq) + lo;
  }
  const int m0 = (bid / gridDim.x) * 256, n0 = (bid % gridDim.x) * 256;

  // staging: thread t covers (row = h*128 + t>>2, slot = t&3) for h=0,1 in
  // each of A,B. LDS linear index = h*4096 + t*8 shorts; since 128 rows *
  // 32 shorts = 4096, rows 0..255 are exactly linear r*32 + slot*8.
  // Source chunk for slot s of row r is s ^ (r&3) ^ (((r>>2)&1)<<1); with
  // r = h*128 + (t>>2) this is constant per thread (h*128 = 0 mod 8):
  const int rr_ = tid >> 2;
  const int csrc =
      (((tid & 3) ^ ((tid >> 2) & 3) ^ (((tid >> 4) & 1) << 1)) << 3);
  const unsigned short* pA0 = A + (size_t)min(m0 + rr_, M - 1) * K + csrc;
  const unsigned short* pA1 = A + (size_t)min(m0 + 128 + rr_, M - 1) * K + csrc;
  const unsigned short* pB0 = Bt + (size_t)(n0 + rr_) * K + csrc;
  const unsigned short* pB1 = Bt + (size_t)(n0 + 128 + rr_) * K + csrc;

  // ds_read: lane (ln15,quad) wants global chunk=quad of row (..+ln15):
  const int rslot =
      ((quad ^ (ln15 & 3) ^ (((ln15 >> 2) & 1) << 1)) << 3);

  const f32x4 fz = {0.f, 0.f, 0.f, 0.f};
  f32x4 acc[8][4];
#pragma unroll
  for (int i = 0; i < 8; i++)
#pragma unroll
    for (int j = 0; j < 4; j++) acc[i][j] = fz;

#define STAGE(BUF, KT)                                                        \
  do {                                                                        \
    unsigned short* d_ = &smem[BUF][0] + tid * 8;                             \
    gload_lds16(pA0 + (KT), d_);                                              \
    gload_lds16(pA1 + (KT), d_ + 4096);                                       \
    gload_lds16(pB0 + (KT), d_ + 8192);                                       \
    gload_lds16(pB1 + (KT), d_ + 12288);                                      \
  } while (0)

  // prologue: stage tile 0, drain, barrier
  STAGE(0, 0);
  asm volatile("s_waitcnt vmcnt(0)" ::: "memory");
  __builtin_amdgcn_sched_barrier(0);
  __builtin_amdgcn_s_barrier();

  int cur = 0;
  for (int kt = 0; kt < K; kt += 32) {
    const bool more = (kt + 32 < K);
    if (more) STAGE(cur ^ 1, kt + 32);  // issue next-tile DMA before compute
    bf16x8 af[8], bv[4];
    const unsigned short* cb = &smem[cur][0];
#pragma unroll
    for (int fj = 0; fj < 4; fj++)
      bv[fj] = ld8(cb + 8192 + (wn * 64 + fj * 16 + ln15) * 32 + rslot);
#pragma unroll
    for (int fi = 0; fi < 8; fi++)
      af[fi] = ld8(cb + (wm * 128 + fi * 16 + ln15) * 32 + rslot);
#pragma unroll
    for (int fi = 0; fi < 8; fi++)
#pragma unroll
      for (int fj = 0; fj < 4; fj++)
        acc[fi][fj] =
            __builtin_amdgcn_mfma_f32_16x16x32_bf16(af[fi], bv[fj], acc[fi][fj], 0, 0, 0);
    if (more) {
      asm volatile("s_waitcnt vmcnt(0)" ::: "memory");  // next tile landed
      __builtin_amdgcn_sched_barrier(0);
      __builtin_amdgcn_s_barrier();
    }
    cur ^= 1;
  }
#undef STAGE

  // Epilogue. C/D layout: col = lane&15, row = quad*4 + reg (verified m89/m91).
#pragma unroll
  for (int i = 0; i < 8; i++) {
#pragma unroll
    for (int j = 0; j < 4; j++) {
      const int col = n0 + wn * 64 + j * 16 + ln15;
      const float bc = bias[col];
#pragma unroll
      for (int g = 0; g < 4; g++) {
        const int row = m0 + wm * 128 + i * 16 + quad * 4 + g;
        if (row >= M) continue;
        float v = acc[i][j][g] + bc;
        if constexpr (EPI == 0) {
          obf[(size_t)row * N + col] = f2bf(v);
        } else if constexpr (EPI == 2) {
          float gl = 0.5f * v * (1.0f + erff(v * 0.70710678118f));
          obf[(size_t)row * N + col] = f2bf(gl);
        } else if constexpr (EPI == 1) {
          // row -> (b,h,w) via window unpartition; drop padded positions
          int win = row / 196, t = row - win * 196;
          int b = win / 25, wg = win - b * 25;
          int wr = wg / 5, wc = wg - wr * 5;
          int h = wr * 14 + t / 14;
          int w = wc * 14 + (t % 14);
          if (h < 64 && w < 64) {
            size_t oi = (((size_t)(b * 64 + h)) * 64 + w) * 768 + col;
            of[oi] = v + resid[oi];
          }
        } else {  // EPI == 3
          size_t oi = (size_t)row * N + col;
          of[oi] += v;
        }
      }
    }
  }
}

// ---------------------------------------------------------------------------
// Fused windowed attention: one block per (window, head). 2400 blocks.
// qkv: bf16 [200*196][2304]; q cols h*64.., k cols 768+h*64.., v 1536+h*64..
// S = (Q Kt)*0.125 + Sh[qr,kr] + Sw[qc,kc]; softmax; O = P V.
// Q/K fragments read directly from global (L1-resident); V transposed in LDS;
// P strip round-trips LDS per wave (C-layout -> A-layout).
// ---------------------------------------------------------------------------
__global__ __launch_bounds__(256, 2) void attn_kernel(
    const unsigned short* __restrict__ qkv, const int* __restrict__ q_idx,
    const int* __restrict__ k_idx, const float* __restrict__ shsw,
    unsigned short* __restrict__ attnout) {
  __shared__ __align__(16) unsigned short Vt[64][232];   // [channel][key] pad->2-way banks
  __shared__ __align__(16) unsigned short Pst[4][16 * 232];  // per-wave P strip
  __shared__ float Shs[196], Sws[196];
  __shared__ short qr14a[208], qc14a[208], kra[208], kca[208];

  const int tid = threadIdx.x;
  const int blk = blockIdx.x;
  const int win = blk / 12, head = blk % 12;
  const int lane = tid & 63, wv = tid >> 6;
  const int ln15 = lane & 15, quad = lane >> 4;
  const unsigned short* qg = qkv + (size_t)win * 196 * 2304;

  // zero Vt & Pst (covers key/col padding 196..223 and strip cols 208..223)
  {
    unsigned int* vz = (unsigned int*)&Vt[0][0];
    for (int i = tid; i < 64 * 232 / 2; i += 256) vz[i] = 0u;
    unsigned int* pz = (unsigned int*)&Pst[0][0];
    for (int i = tid; i < 4 * 16 * 232 / 2; i += 256) pz[i] = 0u;
  }
  // V -> Vt transposed
  for (int i = tid; i < 196 * 64; i += 256) {
    int r = i >> 6, c = i & 63;
    Vt[c][r] = qg[(size_t)r * 2304 + 1536 + head * 64 + c];
  }
  // bias tables + index arrays
  for (int i = tid; i < 208; i += 256) {
    if (i < 196) {
      Shs[i] = shsw[i];
      Sws[i] = shsw[196 + i];
    }
    int q = (i < 196) ? q_idx[(size_t)blk * 196 + i] : 0;
    int k = (i < 196) ? k_idx[(size_t)blk * 196 + i] : 0;
    qr14a[i] = (short)((q / 14) * 14);
    qc14a[i] = (short)((q % 14) * 14);
    kra[i] = (short)(k / 14);
    kca[i] = (short)(k % 14);
  }
  __syncthreads();

  const f32x4 fz = {0.f, 0.f, 0.f, 0.f};
  unsigned short* strip = &Pst[wv][0];

  for (int mt = wv; mt < 13; mt += 4) {
    // ---- Q fragments (A-layout: m=lane&15, k=quad*8+j) from global ----
    int qrow = mt * 16 + ln15;
    int qrc = (qrow < 196) ? qrow : 0;
    const unsigned short* qrp = qg + (size_t)qrc * 2304 + head * 64 + quad * 8;
    bf16x8 aq0 = ld8(qrp);
    bf16x8 aq1 = ld8(qrp + 32);

    // ---- S = Q K^T over 13 col tiles ----
    f32x4 sacc[13];
#pragma unroll
    for (int nt = 0; nt < 13; nt++) {
      sacc[nt] = fz;
      int krow = nt * 16 + ln15;
      if (krow > 195) krow = 0;
      const unsigned short* krp =
          qg + (size_t)krow * 2304 + 768 + head * 64 + quad * 8;
      bf16x8 bk0 = ld8(krp);
      bf16x8 bk1 = ld8(krp + 32);
      sacc[nt] = __builtin_amdgcn_mfma_f32_16x16x32_bf16(aq0, bk0, sacc[nt], 0, 0, 0);
      sacc[nt] = __builtin_amdgcn_mfma_f32_16x16x32_bf16(aq1, bk1, sacc[nt], 0, 0, 0);
    }

    // ---- softmax (rows = quad*4+g of this mt tile) ----
    const int r0 = mt * 16 + quad * 4;
    int qi[4], qci[4];
#pragma unroll
    for (int g = 0; g < 4; g++) {
      qi[g] = qr14a[r0 + g];
      qci[g] = qc14a[r0 + g];
    }
    float rmax[4] = {-1e30f, -1e30f, -1e30f, -1e30f};
#pragma unroll
    for (int nt = 0; nt < 13; nt++) {
      int col = nt * 16 + ln15;
      int kr_ = kra[col], kc_ = kca[col];
#pragma unroll
      for (int g = 0; g < 4; g++) {
        float v = sacc[nt][g] * 0.125f + Shs[qi[g] + kr_] + Sws[qci[g] + kc_];
        if (col >= 196) v = -1e30f;
        sacc[nt][g] = v;
        rmax[g] = fmaxf(rmax[g], v);
      }
    }
#pragma unroll
    for (int off = 1; off < 16; off <<= 1)
#pragma unroll
      for (int g = 0; g < 4; g++)
        rmax[g] = fmaxf(rmax[g], __shfl_xor(rmax[g], off, 16));
    float rsum[4] = {0.f, 0.f, 0.f, 0.f};
#pragma unroll
    for (int nt = 0; nt < 13; nt++) {
      int col = nt * 16 + ln15;
#pragma unroll
      for (int g = 0; g < 4; g++) {
        float p = (col >= 196) ? 0.f : __expf(sacc[nt][g] - rmax[g]);
        sacc[nt][g] = p;
        rsum[g] += p;
      }
    }
#pragma unroll
    for (int off = 1; off < 16; off <<= 1)
#pragma unroll
      for (int g = 0; g < 4; g++) rsum[g] += __shfl_xor(rsum[g], off, 16);
    float rinv[4];
#pragma unroll
    for (int g = 0; g < 4; g++) rinv[g] = 1.0f / rsum[g];

    // ---- write P strip (row-major [16][232] bf16, A-layout source for PV) ----
#pragma unroll
    for (int nt = 0; nt < 13; nt++) {
      int col = nt * 16 + ln15;
#pragma unroll
      for (int g = 0; g < 4; g++)
        strip[(quad * 4 + g) * 232 + col] = f2bf(sacc[nt][g] * rinv[g]);
    }

    // ---- O = P V  (K padded to 224; strip/Vt zeros beyond 196) ----
    f32x4 oacc[4];
#pragma unroll
    for (int c4 = 0; c4 < 4; c4++) oacc[c4] = fz;
#pragma unroll
    for (int ks = 0; ks < 7; ks++) {
      bf16x8 ap = ld8(strip + ln15 * 232 + ks * 32 + quad * 8);
#pragma unroll
      for (int c4 = 0; c4 < 4; c4++) {
        bf16x8 bvv = ld8(&Vt[c4 * 16 + ln15][ks * 32 + quad * 8]);
        oacc[c4] = __builtin_amdgcn_mfma_f32_16x16x32_bf16(ap, bvv, oacc[c4], 0, 0, 0);
      }
    }
    // ---- store (C-layout: col=lane&15 channel, row=quad*4+g token) ----
#pragma unroll
    for (int c4 = 0; c4 < 4; c4++)
#pragma unroll
      for (int g = 0; g < 4; g++) {
        int row = r0 + g;
        if (row < 196)
          attnout[((size_t)win * 196 + row) * 768 + head * 64 + c4 * 16 + ln15] =
              f2bf(oacc[c4][g]);
      }
  }
}

// ---------------------------------------------------------------------------
// Launch. Workspace layout (bytes):
//   [0, 60211200)              region A: xw bf16 [39200][768] -> attnout -> ln2
//   [60211200, 261537792)      region B: qkv bf16 [39200][2304] -> mlp1 [32768][3072]
//   [261537792, ...)           transposed weights bf16 + ShSw tables (~14.2 MB)
// Peak ws use ~276 MB.
// ---------------------------------------------------------------------------
extern "C" void kernel_launch(void* const* d_in, const int* in_sizes, int n_in,
                              void* d_out, int out_size, void* d_ws,
                              size_t ws_size, hipStream_t stream) {
  const float* x = (const float*)d_in[0];
  const int* q_idx = (const int*)d_in[1];
  const int* k_idx = (const int*)d_in[2];
  const float* ln1w = (const float*)d_in[3];
  const float* ln1b = (const float*)d_in[4];
  const float* ln2w = (const float*)d_in[5];
  const float* ln2b = (const float*)d_in[6];
  const float* qkvw = (const float*)d_in[7];
  const float* qkvb = (const float*)d_in[8];
  const float* projw = (const float*)d_in[9];
  const float* projb = (const float*)d_in[10];
  const float* relh = (const float*)d_in[11];
  const float* relw = (const float*)d_in[12];
  const float* w1 = (const float*)d_in[13];
  const float* b1 = (const float*)d_in[14];
  const float* w2 = (const float*)d_in[15];
  const float* b2 = (const float*)d_in[16];
  float* out = (float*)d_out;

  char* ws = (char*)d_ws;
  unsigned short* xw = (unsigned short*)ws;  // region A
  const size_t offA = 60211200;              // 39200*768*2
  unsigned short* qkv = (unsigned short*)(ws + offA);  // region B
  const size_t offB = offA + 201326592;      // max(qkv, mlp1)
  unsigned short* qkvwt = (unsigned short*)(ws + offB);
  unsigned short* projwt = qkvwt + 2304 * 768;
  unsigned short* w1t = projwt + 768 * 768;
  unsigned short* w2t = w1t + 3072 * 768;
  float* shsw = (float*)(w2t + 768 * 3072);

  unsigned short* attnout = xw;  // region A reuse (xw dead after qkv GEMM)
  unsigned short* ln2buf = xw;   // region A reuse (attnout dead after proj)
  unsigned short* mlp1 = qkv;    // region B reuse (qkv dead after attention)

  // zero xw so spatially-padded window tokens are zero feature vectors
  hipMemsetAsync(xw, 0, (size_t)39200 * 768 * 2, stream);

  dim3 tb(32, 8);
  transpose_w<<<dim3(2304 / 32, 768 / 32), tb, 0, stream>>>(qkvw, qkvwt, 768, 2304);
  transpose_w<<<dim3(768 / 32, 768 / 32), tb, 0, stream>>>(projw, projwt, 768, 768);
  transpose_w<<<dim3(3072 / 32, 768 / 32), tb, 0, stream>>>(w1, w1t, 768, 3072);
  transpose_w<<<dim3(768 / 32, 3072 / 32), tb, 0, stream>>>(w2, w2t, 3072, 768);
  shsw_kernel<<<1, 256, 0, stream>>>(relh, relw, shsw);

  // LN1 + window partition -> bf16
  ln_kernel<<<32768, 256, 0, stream>>>(x, ln1w, ln1b, xw, 1);

  // qkv = xw @ qkv_w + b   [39200,768]x[768,2304]  (154x9 tiles of 256)
  gemm_bt<0><<<dim3(9, 154), 512, 0, stream>>>(xw, qkvwt, qkvb, 39200, 2304,
                                               768, qkv, nullptr, nullptr);
  // fused windowed attention
  attn_kernel<<<2400, 256, 0, stream>>>(qkv, q_idx, k_idx, shsw, attnout);

  // proj + residual + unpartition -> d_out (fp32 x_mid)
  gemm_bt<1><<<dim3(3, 154), 512, 0, stream>>>(attnout, projwt, projb, 39200,
                                               768, 768, nullptr, out, x);
  // LN2 -> bf16
  ln_kernel<<<32768, 256, 0, stream>>>(out, ln2w, ln2b, ln2buf, 0);

  // mlp1 = gelu(ln2 @ w1 + b1)   [32768,768]x[768,3072]
  gemm_bt<2><<<dim3(12, 128), 512, 0, stream>>>(ln2buf, w1t, b1, 32768, 3072,
                                                768, mlp1, nullptr, nullptr);
  // d_out += mlp1 @ w2 + b2      [32768,3072]x[3072,768]
  gemm_bt<3><<<dim3(3, 128), 512, 0, stream>>>(mlp1, w2t, b2, 32768, 768, 3072,
                                               nullptr, out, nullptr);
  (void)in_sizes; (void)n_in; (void)out_size; (void)ws_size;
}

// Round 5
// 1332.572 us; speedup vs baseline: 1.1011x; 1.1011x over previous
//
#include <hip/hip_runtime.h>

// ---------------------------------------------------------------------------
// SAM windowed-attention block, bf16-MFMA implementation.
// B=8 H=W=64 DIM=768 NH=12 HD=64 WS=14 N=196 PAD=6 -> 70x70, 5x5=25 windows,
// Bp=200 windows, 2400 (window,head) pairs. All GEMMs bf16 MFMA 16x16x32,
// fp32 accumulate. Softmax/LN/gelu in fp32.
// R5: R3's 128x128 structure + pipeline depth 2: triple-buffered LDS
// (3 x 16KB = 48KB, 3 blocks/CU), stage tile t+2 per iter, counted
// s_waitcnt vmcnt(4) (tile t+1 landed, t+2 stays in flight across the
// barrier -- T4). R4 showed the limiter is per-tile staging-latency
// exposure, not bandwidth: depth-2 gives ~2 tiles of compute to hide it.
// ---------------------------------------------------------------------------

typedef __bf16 bf16x8 __attribute__((ext_vector_type(8)));
typedef float f32x4 __attribute__((ext_vector_type(4)));
typedef unsigned int u32x4 __attribute__((ext_vector_type(4)));

__device__ __forceinline__ unsigned short f2bf(float f) {
  unsigned int u = __builtin_bit_cast(unsigned int, f);
  u += 0x7FFFu + ((u >> 16) & 1u);
  return (unsigned short)(u >> 16);
}

__device__ __forceinline__ bf16x8 ld8(const unsigned short* p) {
  return __builtin_bit_cast(bf16x8, *(const u32x4*)p);
}

// async global->LDS, 16B per lane. LDS dest must be wave-uniform base + lane*16.
__device__ __forceinline__ void gload_lds16(const unsigned short* g,
                                            unsigned short* l) {
  __builtin_amdgcn_global_load_lds(
      (const __attribute__((address_space(1))) unsigned int*)g,
      (__attribute__((address_space(3))) unsigned int*)l, 16, 0, 0);
}

// ---------------------------------------------------------------------------
// Weight transpose fp32[K][N] -> bf16[N][K]  (all dims multiples of 32)
// ---------------------------------------------------------------------------
__global__ void transpose_w(const float* __restrict__ in,
                            unsigned short* __restrict__ out, int K, int N) {
  __shared__ float t[32][33];
  int n = blockIdx.x * 32 + threadIdx.x;
  int kb = blockIdx.y * 32;
#pragma unroll
  for (int i = 0; i < 4; i++) {
    int k = kb + threadIdx.y + i * 8;
    t[threadIdx.y + i * 8][threadIdx.x] = in[(size_t)k * N + n];
  }
  __syncthreads();
  int k2 = kb + threadIdx.x;
#pragma unroll
  for (int i = 0; i < 4; i++) {
    int n2 = blockIdx.x * 32 + threadIdx.y + i * 8;
    out[(size_t)n2 * K + k2] = f2bf(t[threadIdx.x][threadIdx.y + i * 8]);
  }
}

// ---------------------------------------------------------------------------
// Rel-pos tables: Sh[i*14+j] = sum_c rel_h[(i-j+13)*64+c]; same for Sw.
// out layout: [0..195]=Sh, [196..391]=Sw
// ---------------------------------------------------------------------------
__global__ void shsw_kernel(const float* __restrict__ rh,
                            const float* __restrict__ rw,
                            float* __restrict__ o) {
  int t = threadIdx.x;
  if (t < 196) {
    int i = t / 14, j = t % 14, d = i - j + 13;
    float sh = 0.f, sw = 0.f;
    for (int c = 0; c < 64; c++) {
      sh += rh[d * 64 + c];
      sw += rw[d * 64 + c];
    }
    o[t] = sh;
    o[196 + t] = sw;
  }
}

// ---------------------------------------------------------------------------
// LayerNorm over 768. windowed=1: write to window-partitioned layout
// [win*196+t][768]; windowed=0: write [row][768]. Output bf16.
// ---------------------------------------------------------------------------
__global__ __launch_bounds__(256) void ln_kernel(
    const float* __restrict__ xin, const float* __restrict__ w,
    const float* __restrict__ b, unsigned short* __restrict__ out,
    int windowed) {
  __shared__ float red[8];
  __shared__ float ms[2];
  const int tid = threadIdx.x;
  const int blk = blockIdx.x;
  const float* xr = xin + (size_t)blk * 768;
  float v0 = xr[tid], v1 = xr[tid + 256], v2 = xr[tid + 512];
  float s = v0 + v1 + v2;
  float q = v0 * v0 + v1 * v1 + v2 * v2;
#pragma unroll
  for (int off = 32; off > 0; off >>= 1) {
    s += __shfl_down(s, off, 64);
    q += __shfl_down(q, off, 64);
  }
  const int wv = tid >> 6, lane = tid & 63;
  if (lane == 0) { red[wv] = s; red[4 + wv] = q; }
  __syncthreads();
  if (tid == 0) {
    float st = red[0] + red[1] + red[2] + red[3];
    float qt = red[4] + red[5] + red[6] + red[7];
    float mu = st * (1.0f / 768.0f);
    float var = qt * (1.0f / 768.0f) - mu * mu;
    ms[0] = mu;
    ms[1] = rsqrtf(var + 1e-5f);
  }
  __syncthreads();
  float mu = ms[0], sc = ms[1];
  unsigned short* dst;
  if (windowed) {
    int bb = blk >> 12, rem = blk & 4095, h = rem >> 6, ww = rem & 63;
    int win = (bb * 5 + h / 14) * 5 + ww / 14;
    int t = (h % 14) * 14 + (ww % 14);
    dst = out + ((size_t)win * 196 + t) * 768;
  } else {
    dst = out + (size_t)blk * 768;
  }
  dst[tid] = f2bf((v0 - mu) * sc * w[tid] + b[tid]);
  dst[tid + 256] = f2bf((v1 - mu) * sc * w[tid + 256] + b[tid + 256]);
  dst[tid + 512] = f2bf((v2 - mu) * sc * w[tid + 512] + b[tid + 512]);
}

// ---------------------------------------------------------------------------
// bf16 GEMM: C[M][N] = A[M][K] @ Bt[N][K]^T (+ epilogue)
// 128x128 block tile, BK=32, 4 waves in 2x2, each wave 64x64 (4x4 MFMA tiles).
// Triple-buffered LDS (3 x 16KB): at iter t, STAGE(t+2) is issued first
// (global_load_lds DMA, 8 loads in flight total), then ds_read+MFMA on
// buf[t], then s_waitcnt vmcnt(4) -- tile t+1's 4 loads landed, tile t+2's
// stay in flight ACROSS the barrier (counted-vmcnt, T4). buf[t] is only
// overwritten when staging t+3 at iter t+1, one barrier after its last read.
// LDS tile layout [128 rows][4 chunks of 16B], swizzled:
//   slot = chunk ^ (row&3) ^ (((row>>2)&1)<<1)   (verified: 0 conflicts)
// DMA dest stays linear (tid*16B); the global SOURCE is inverse-permuted.
// Requires K >= 64 (all call sites: K=768 or 3072).
// EPI: 0=+bias->bf16 (qkv), 1=+bias+resid, window-unpartition ->fp32 d_out
//      2=+bias,gelu->bf16 (mlp1), 3=+bias, d_out += (mlp2)
// ---------------------------------------------------------------------------
template <int EPI>
__global__ __launch_bounds__(256, 2) void gemm_bt(
    const unsigned short* __restrict__ A, const unsigned short* __restrict__ Bt,
    const float* __restrict__ bias, int M, int N, int K,
    unsigned short* __restrict__ obf, float* __restrict__ of,
    const float* __restrict__ resid) {
  __shared__ __align__(16) unsigned short smem[3][8192];  // [buf][A:0..4096|B:4096..8192]
  const int tid = threadIdx.x;
  const int lane = tid & 63, wv = tid >> 6;
  const int ln15 = lane & 15, quad = lane >> 4;
  const int wm = wv & 1, wn = wv >> 1;

  // bijective XCD-chunked swizzle (8 XCDs)
  int bid = blockIdx.y * gridDim.x + blockIdx.x;
  {
    const int nwg = gridDim.x * gridDim.y;
    const int qq = nwg >> 3, rr = nwg & 7;
    const int xcd = bid & 7, lo = bid >> 3;
    bid = (xcd < rr ? xcd * (qq + 1) : rr * (qq + 1) + (xcd - rr) * qq) + lo;
  }
  const int m0 = (bid / gridDim.x) * 128, n0 = (bid % gridDim.x) * 128;

  // staging: thread t covers (row = q*64 + t>>2, slot = t&3) for q=0,1 in each
  // of A,B. LDS linear index = q*2048 + t*8 (wave-uniform base + lane*16B).
  // Source chunk for slot s of row r is s ^ (r&3) ^ (((r>>2)&1)<<1); with
  // r = q*64 + (t>>2) this is constant per thread:
  const int rr_ = tid >> 2;
  const int csrc =
      (((tid & 3) ^ ((tid >> 2) & 3) ^ (((tid >> 4) & 1) << 1)) << 3);
  const unsigned short* pA0 = A + (size_t)min(m0 + rr_, M - 1) * K + csrc;
  const unsigned short* pA1 = A + (size_t)min(m0 + 64 + rr_, M - 1) * K + csrc;
  const unsigned short* pB0 = Bt + (size_t)(n0 + rr_) * K + csrc;
  const unsigned short* pB1 = Bt + (size_t)(n0 + 64 + rr_) * K + csrc;

  // ds_read: lane (ln15,quad) wants global chunk=quad of row (..+ln15):
  const int rslot =
      ((quad ^ (ln15 & 3) ^ (((ln15 >> 2) & 1) << 1)) << 3);

  const f32x4 fz = {0.f, 0.f, 0.f, 0.f};
  f32x4 acc[4][4];
#pragma unroll
  for (int i = 0; i < 4; i++)
#pragma unroll
    for (int j = 0; j < 4; j++) acc[i][j] = fz;

#define STAGE(BASE, KT)                                                       \
  do {                                                                        \
    unsigned short* d_ = (BASE) + tid * 8;                                    \
    gload_lds16(pA0 + (KT), d_);                                              \
    gload_lds16(pA1 + (KT), d_ + 2048);                                       \
    gload_lds16(pB0 + (KT), d_ + 4096);                                       \
    gload_lds16(pB1 + (KT), d_ + 6144);                                       \
  } while (0)

  unsigned short* cb = &smem[0][0];
  unsigned short* nb = &smem[1][0];
  unsigned short* fb = &smem[2][0];

  // prologue: stage tiles 0 and 1 (K >= 64 guaranteed); wait for tile 0 only
  STAGE(cb, 0);
  STAGE(nb, 32);
  asm volatile("s_waitcnt vmcnt(4)" ::: "memory");
  __builtin_amdgcn_sched_barrier(0);
  __builtin_amdgcn_s_barrier();

  for (int kt = 0; kt < K; kt += 32) {
    const bool more2 = (kt + 64 < K);
    if (more2) STAGE(fb, kt + 64);  // depth-2 prefetch, stays in flight
    bf16x8 af[4], bv[4];
#pragma unroll
    for (int t = 0; t < 4; t++) {
      af[t] = ld8(cb + (wm * 64 + t * 16 + ln15) * 32 + rslot);
      bv[t] = ld8(cb + 4096 + (wn * 64 + t * 16 + ln15) * 32 + rslot);
    }
#pragma unroll
    for (int i = 0; i < 4; i++)
#pragma unroll
      for (int j = 0; j < 4; j++)
        acc[i][j] =
            __builtin_amdgcn_mfma_f32_16x16x32_bf16(af[i], bv[j], acc[i][j], 0, 0, 0);
    const bool more = (kt + 32 < K);
    if (more) {
      if (more2) {
        asm volatile("s_waitcnt vmcnt(4)" ::: "memory");  // tile t+1 landed
      } else {
        asm volatile("s_waitcnt vmcnt(0)" ::: "memory");  // tail drain
      }
      __builtin_amdgcn_sched_barrier(0);
      __builtin_amdgcn_s_barrier();
    }
    unsigned short* tmp = cb;
    cb = nb;
    nb = fb;
    fb = tmp;
  }
#undef STAGE

  // Epilogue. C/D layout: col = lane&15, row = quad*4 + reg (verified m89/m91).
#pragma unroll
  for (int i = 0; i < 4; i++) {
#pragma unroll
    for (int j = 0; j < 4; j++) {
      const int col = n0 + wn * 64 + j * 16 + ln15;
      const float bc = bias[col];
#pragma unroll
      for (int g = 0; g < 4; g++) {
        const int row = m0 + wm * 64 + i * 16 + quad * 4 + g;
        if (row >= M) continue;
        float v = acc[i][j][g] + bc;
        if constexpr (EPI == 0) {
          obf[(size_t)row * N + col] = f2bf(v);
        } else if constexpr (EPI == 2) {
          float gl = 0.5f * v * (1.0f + erff(v * 0.70710678118f));
          obf[(size_t)row * N + col] = f2bf(gl);
        } else if constexpr (EPI == 1) {
          // row -> (b,h,w) via window unpartition; drop padded positions
          int win = row / 196, t = row - win * 196;
          int b = win / 25, wg = win - b * 25;
          int wr = wg / 5, wc = wg - wr * 5;
          int h = wr * 14 + t / 14;
          int w = wc * 14 + (t % 14);
          if (h < 64 && w < 64) {
            size_t oi = (((size_t)(b * 64 + h)) * 64 + w) * 768 + col;
            of[oi] = v + resid[oi];
          }
        } else {  // EPI == 3
          size_t oi = (size_t)row * N + col;
          of[oi] += v;
        }
      }
    }
  }
}

// ---------------------------------------------------------------------------
// Fused windowed attention: one block per (window, head). 2400 blocks.
// qkv: bf16 [200*196][2304]; q cols h*64.., k cols 768+h*64.., v 1536+h*64..
// S = (Q Kt)*0.125 + Sh[qr,kr] + Sw[qc,kc]; softmax; O = P V.
// Q/K fragments read directly from global (L1-resident); V transposed in LDS;
// P strip round-trips LDS per wave (C-layout -> A-layout).
// ---------------------------------------------------------------------------
__global__ __launch_bounds__(256, 2) void attn_kernel(
    const unsigned short* __restrict__ qkv, const int* __restrict__ q_idx,
    const int* __restrict__ k_idx, const float* __restrict__ shsw,
    unsigned short* __restrict__ attnout) {
  __shared__ __align__(16) unsigned short Vt[64][232];   // [channel][key] pad->2-way banks
  __shared__ __align__(16) unsigned short Pst[4][16 * 232];  // per-wave P strip
  __shared__ float Shs[196], Sws[196];
  __shared__ short qr14a[208], qc14a[208], kra[208], kca[208];

  const int tid = threadIdx.x;
  const int blk = blockIdx.x;
  const int win = blk / 12, head = blk % 12;
  const int lane = tid & 63, wv = tid >> 6;
  const int ln15 = lane & 15, quad = lane >> 4;
  const unsigned short* qg = qkv + (size_t)win * 196 * 2304;

  // zero Vt & Pst (covers key/col padding 196..223 and strip cols 208..223)
  {
    unsigned int* vz = (unsigned int*)&Vt[0][0];
    for (int i = tid; i < 64 * 232 / 2; i += 256) vz[i] = 0u;
    unsigned int* pz = (unsigned int*)&Pst[0][0];
    for (int i = tid; i < 4 * 16 * 232 / 2; i += 256) pz[i] = 0u;
  }
  // V -> Vt transposed
  for (int i = tid; i < 196 * 64; i += 256) {
    int r = i >> 6, c = i & 63;
    Vt[c][r] = qg[(size_t)r * 2304 + 1536 + head * 64 + c];
  }
  // bias tables + index arrays
  for (int i = tid; i < 208; i += 256) {
    if (i < 196) {
      Shs[i] = shsw[i];
      Sws[i] = shsw[196 + i];
    }
    int q = (i < 196) ? q_idx[(size_t)blk * 196 + i] : 0;
    int k = (i < 196) ? k_idx[(size_t)blk * 196 + i] : 0;
    qr14a[i] = (short)((q / 14) * 14);
    qc14a[i] = (short)((q % 14) * 14);
    kra[i] = (short)(k / 14);
    kca[i] = (short)(k % 14);
  }
  __syncthreads();

  const f32x4 fz = {0.f, 0.f, 0.f, 0.f};
  unsigned short* strip = &Pst[wv][0];

  for (int mt = wv; mt < 13; mt += 4) {
    // ---- Q fragments (A-layout: m=lane&15, k=quad*8+j) from global ----
    int qrow = mt * 16 + ln15;
    int qrc = (qrow < 196) ? qrow : 0;
    const unsigned short* qrp = qg + (size_t)qrc * 2304 + head * 64 + quad * 8;
    bf16x8 aq0 = ld8(qrp);
    bf16x8 aq1 = ld8(qrp + 32);

    // ---- S = Q K^T over 13 col tiles ----
    f32x4 sacc[13];
#pragma unroll
    for (int nt = 0; nt < 13; nt++) {
      sacc[nt] = fz;
      int krow = nt * 16 + ln15;
      if (krow > 195) krow = 0;
      const unsigned short* krp =
          qg + (size_t)krow * 2304 + 768 + head * 64 + quad * 8;
      bf16x8 bk0 = ld8(krp);
      bf16x8 bk1 = ld8(krp + 32);
      sacc[nt] = __builtin_amdgcn_mfma_f32_16x16x32_bf16(aq0, bk0, sacc[nt], 0, 0, 0);
      sacc[nt] = __builtin_amdgcn_mfma_f32_16x16x32_bf16(aq1, bk1, sacc[nt], 0, 0, 0);
    }

    // ---- softmax (rows = quad*4+g of this mt tile) ----
    const int r0 = mt * 16 + quad * 4;
    int qi[4], qci[4];
#pragma unroll
    for (int g = 0; g < 4; g++) {
      qi[g] = qr14a[r0 + g];
      qci[g] = qc14a[r0 + g];
    }
    float rmax[4] = {-1e30f, -1e30f, -1e30f, -1e30f};
#pragma unroll
    for (int nt = 0; nt < 13; nt++) {
      int col = nt * 16 + ln15;
      int kr_ = kra[col], kc_ = kca[col];
#pragma unroll
      for (int g = 0; g < 4; g++) {
        float v = sacc[nt][g] * 0.125f + Shs[qi[g] + kr_] + Sws[qci[g] + kc_];
        if (col >= 196) v = -1e30f;
        sacc[nt][g] = v;
        rmax[g] = fmaxf(rmax[g], v);
      }
    }
#pragma unroll
    for (int off = 1; off < 16; off <<= 1)
#pragma unroll
      for (int g = 0; g < 4; g++)
        rmax[g] = fmaxf(rmax[g], __shfl_xor(rmax[g], off, 16));
    float rsum[4] = {0.f, 0.f, 0.f, 0.f};
#pragma unroll
    for (int nt = 0; nt < 13; nt++) {
      int col = nt * 16 + ln15;
#pragma unroll
      for (int g = 0; g < 4; g++) {
        float p = (col >= 196) ? 0.f : __expf(sacc[nt][g] - rmax[g]);
        sacc[nt][g] = p;
        rsum[g] += p;
      }
    }
#pragma unroll
    for (int off = 1; off < 16; off <<= 1)
#pragma unroll
      for (int g = 0; g < 4; g++) rsum[g] += __shfl_xor(rsum[g], off, 16);
    float rinv[4];
#pragma unroll
    for (int g = 0; g < 4; g++) rinv[g] = 1.0f / rsum[g];

    // ---- write P strip (row-major [16][232] bf16, A-layout source for PV) ----
#pragma unroll
    for (int nt = 0; nt < 13; nt++) {
      int col = nt * 16 + ln15;
#pragma unroll
      for (int g = 0; g < 4; g++)
        strip[(quad * 4 + g) * 232 + col] = f2bf(sacc[nt][g] * rinv[g]);
    }

    // ---- O = P V  (K padded to 224; strip/Vt zeros beyond 196) ----
    f32x4 oacc[4];
#pragma unroll
    for (int c4 = 0; c4 < 4; c4++) oacc[c4] = fz;
#pragma unroll
    for (int ks = 0; ks < 7; ks++) {
      bf16x8 ap = ld8(strip + ln15 * 232 + ks * 32 + quad * 8);
#pragma unroll
      for (int c4 = 0; c4 < 4; c4++) {
        bf16x8 bvv = ld8(&Vt[c4 * 16 + ln15][ks * 32 + quad * 8]);
        oacc[c4] = __builtin_amdgcn_mfma_f32_16x16x32_bf16(ap, bvv, oacc[c4], 0, 0, 0);
      }
    }
    // ---- store (C-layout: col=lane&15 channel, row=quad*4+g token) ----
#pragma unroll
    for (int c4 = 0; c4 < 4; c4++)
#pragma unroll
      for (int g = 0; g < 4; g++) {
        int row = r0 + g;
        if (row < 196)
          attnout[((size_t)win * 196 + row) * 768 + head * 64 + c4 * 16 + ln15] =
              f2bf(oacc[c4][g]);
      }
  }
}

// ---------------------------------------------------------------------------
// Launch. Workspace layout (bytes):
//   [0, 60211200)              region A: xw bf16 [39200][768] -> attnout -> ln2
//   [60211200, 261537792)      region B: qkv bf16 [39200][2304] -> mlp1 [32768][3072]
//   [261537792, ...)           transposed weights bf16 + ShSw tables (~14.2 MB)
// Peak ws use ~276 MB.
// ---------------------------------------------------------------------------
extern "C" void kernel_launch(void* const* d_in, const int* in_sizes, int n_in,
                              void* d_out, int out_size, void* d_ws,
                              size_t ws_size, hipStream_t stream) {
  const float* x = (const float*)d_in[0];
  const int* q_idx = (const int*)d_in[1];
  const int* k_idx = (const int*)d_in[2];
  const float* ln1w = (const float*)d_in[3];
  const float* ln1b = (const float*)d_in[4];
  const float* ln2w = (const float*)d_in[5];
  const float* ln2b = (const float*)d_in[6];
  const float* qkvw = (const float*)d_in[7];
  const float* qkvb = (const float*)d_in[8];
  const float* projw = (const float*)d_in[9];
  const float* projb = (const float*)d_in[10];
  const float* relh = (const float*)d_in[11];
  const float* relw = (const float*)d_in[12];
  const float* w1 = (const float*)d_in[13];
  const float* b1 = (const float*)d_in[14];
  const float* w2 = (const float*)d_in[15];
  const float* b2 = (const float*)d_in[16];
  float* out = (float*)d_out;

  char* ws = (char*)d_ws;
  unsigned short* xw = (unsigned short*)ws;  // region A
  const size_t offA = 60211200;              // 39200*768*2
  unsigned short* qkv = (unsigned short*)(ws + offA);  // region B
  const size_t offB = offA + 201326592;      // max(qkv, mlp1)
  unsigned short* qkvwt = (unsigned short*)(ws + offB);
  unsigned short* projwt = qkvwt + 2304 * 768;
  unsigned short* w1t = projwt + 768 * 768;
  unsigned short* w2t = w1t + 3072 * 768;
  float* shsw = (float*)(w2t + 768 * 3072);

  unsigned short* attnout = xw;  // region A reuse (xw dead after qkv GEMM)
  unsigned short* ln2buf = xw;   // region A reuse (attnout dead after proj)
  unsigned short* mlp1 = qkv;    // region B reuse (qkv dead after attention)

  // zero xw so spatially-padded window tokens are zero feature vectors
  hipMemsetAsync(xw, 0, (size_t)39200 * 768 * 2, stream);

  dim3 tb(32, 8);
  transpose_w<<<dim3(2304 / 32, 768 / 32), tb, 0, stream>>>(qkvw, qkvwt, 768, 2304);
  transpose_w<<<dim3(768 / 32, 768 / 32), tb, 0, stream>>>(projw, projwt, 768, 768);
  transpose_w<<<dim3(3072 / 32, 768 / 32), tb, 0, stream>>>(w1, w1t, 768, 3072);
  transpose_w<<<dim3(768 / 32, 3072 / 32), tb, 0, stream>>>(w2, w2t, 3072, 768);
  shsw_kernel<<<1, 256, 0, stream>>>(relh, relw, shsw);

  // LN1 + window partition -> bf16
  ln_kernel<<<32768, 256, 0, stream>>>(x, ln1w, ln1b, xw, 1);

  // qkv = xw @ qkv_w + b   [39200,768]x[768,2304]
  gemm_bt<0><<<dim3(18, 307), 256, 0, stream>>>(xw, qkvwt, qkvb, 39200, 2304,
                                                768, qkv, nullptr, nullptr);
  // fused windowed attention
  attn_kernel<<<2400, 256, 0, stream>>>(qkv, q_idx, k_idx, shsw, attnout);

  // proj + residual + unpartition -> d_out (fp32 x_mid)
  gemm_bt<1><<<dim3(6, 307), 256, 0, stream>>>(attnout, projwt, projb, 39200,
                                               768, 768, nullptr, out, x);
  // LN2 -> bf16
  ln_kernel<<<32768, 256, 0, stream>>>(out, ln2w, ln2b, ln2buf, 0);

  // mlp1 = gelu(ln2 @ w1 + b1)   [32768,768]x[768,3072]
  gemm_bt<2><<<dim3(24, 256), 256, 0, stream>>>(ln2buf, w1t, b1, 32768, 3072,
                                                768, mlp1, nullptr, nullptr);
  // d_out += mlp1 @ w2 + b2      [32768,3072]x[3072,768]
  gemm_bt<3><<<dim3(6, 256), 256, 0, stream>>>(mlp1, w2t, b2, 32768, 768, 3072,
                                               nullptr, out, nullptr);
  (void)in_sizes; (void)n_in; (void)out_size; (void)ws_size;
}

// Round 7
// 1331.677 us; speedup vs baseline: 1.1018x; 1.0007x over previous
//
#include <hip/hip_runtime.h>

// ---------------------------------------------------------------------------
// SAM windowed-attention block, bf16-MFMA implementation.
// B=8 H=W=64 DIM=768 NH=12 HD=64 WS=14 N=196 PAD=6 -> 70x70, 5x5=25 windows,
// Bp=200 windows, 2400 (window,head) pairs. GEMMs bf16 MFMA, fp32 accumulate.
// R6 (resubmit; previous round hit GPUAcquisitionTimeout, never benched):
// R3's verified 128x128 2-phase dbuf structure, MFMA shape switched to
// 32x32x16 (per wave 2x2 tiles of 32x32): same 8 ds_read_b128/iter but 8
// fat MFMAs instead of 16 (m119: 2495 vs 2176 TF pipe rate, halved
// lgkm-dependent op count -> shorter per-iter critical path in the
// latency-bound regime R1/R3/R5 all pinned at). C/D layout col=lane&31,
// row=(reg&3)+8*(reg>>2)+4*(lane>>5) (HW-verified m74/m101).
// ---------------------------------------------------------------------------

typedef __bf16 bf16x8 __attribute__((ext_vector_type(8)));
typedef float f32x4 __attribute__((ext_vector_type(4)));
typedef float f32x16 __attribute__((ext_vector_type(16)));
typedef unsigned int u32x4 __attribute__((ext_vector_type(4)));

__device__ __forceinline__ unsigned short f2bf(float f) {
  unsigned int u = __builtin_bit_cast(unsigned int, f);
  u += 0x7FFFu + ((u >> 16) & 1u);
  return (unsigned short)(u >> 16);
}

__device__ __forceinline__ bf16x8 ld8(const unsigned short* p) {
  return __builtin_bit_cast(bf16x8, *(const u32x4*)p);
}

// async global->LDS, 16B per lane. LDS dest must be wave-uniform base + lane*16.
__device__ __forceinline__ void gload_lds16(const unsigned short* g,
                                            unsigned short* l) {
  __builtin_amdgcn_global_load_lds(
      (const __attribute__((address_space(1))) unsigned int*)g,
      (__attribute__((address_space(3))) unsigned int*)l, 16, 0, 0);
}

// ---------------------------------------------------------------------------
// Weight transpose fp32[K][N] -> bf16[N][K]  (all dims multiples of 32)
// ---------------------------------------------------------------------------
__global__ void transpose_w(const float* __restrict__ in,
                            unsigned short* __restrict__ out, int K, int N) {
  __shared__ float t[32][33];
  int n = blockIdx.x * 32 + threadIdx.x;
  int kb = blockIdx.y * 32;
#pragma unroll
  for (int i = 0; i < 4; i++) {
    int k = kb + threadIdx.y + i * 8;
    t[threadIdx.y + i * 8][threadIdx.x] = in[(size_t)k * N + n];
  }
  __syncthreads();
  int k2 = kb + threadIdx.x;
#pragma unroll
  for (int i = 0; i < 4; i++) {
    int n2 = blockIdx.x * 32 + threadIdx.y + i * 8;
    out[(size_t)n2 * K + k2] = f2bf(t[threadIdx.x][threadIdx.y + i * 8]);
  }
}

// ---------------------------------------------------------------------------
// Rel-pos tables: Sh[i*14+j] = sum_c rel_h[(i-j+13)*64+c]; same for Sw.
// out layout: [0..195]=Sh, [196..391]=Sw
// ---------------------------------------------------------------------------
__global__ void shsw_kernel(const float* __restrict__ rh,
                            const float* __restrict__ rw,
                            float* __restrict__ o) {
  int t = threadIdx.x;
  if (t < 196) {
    int i = t / 14, j = t % 14, d = i - j + 13;
    float sh = 0.f, sw = 0.f;
    for (int c = 0; c < 64; c++) {
      sh += rh[d * 64 + c];
      sw += rw[d * 64 + c];
    }
    o[t] = sh;
    o[196 + t] = sw;
  }
}

// ---------------------------------------------------------------------------
// LayerNorm over 768. windowed=1: write to window-partitioned layout
// [win*196+t][768]; windowed=0: write [row][768]. Output bf16.
// ---------------------------------------------------------------------------
__global__ __launch_bounds__(256) void ln_kernel(
    const float* __restrict__ xin, const float* __restrict__ w,
    const float* __restrict__ b, unsigned short* __restrict__ out,
    int windowed) {
  __shared__ float red[8];
  __shared__ float ms[2];
  const int tid = threadIdx.x;
  const int blk = blockIdx.x;
  const float* xr = xin + (size_t)blk * 768;
  float v0 = xr[tid], v1 = xr[tid + 256], v2 = xr[tid + 512];
  float s = v0 + v1 + v2;
  float q = v0 * v0 + v1 * v1 + v2 * v2;
#pragma unroll
  for (int off = 32; off > 0; off >>= 1) {
    s += __shfl_down(s, off, 64);
    q += __shfl_down(q, off, 64);
  }
  const int wv = tid >> 6, lane = tid & 63;
  if (lane == 0) { red[wv] = s; red[4 + wv] = q; }
  __syncthreads();
  if (tid == 0) {
    float st = red[0] + red[1] + red[2] + red[3];
    float qt = red[4] + red[5] + red[6] + red[7];
    float mu = st * (1.0f / 768.0f);
    float var = qt * (1.0f / 768.0f) - mu * mu;
    ms[0] = mu;
    ms[1] = rsqrtf(var + 1e-5f);
  }
  __syncthreads();
  float mu = ms[0], sc = ms[1];
  unsigned short* dst;
  if (windowed) {
    int bb = blk >> 12, rem = blk & 4095, h = rem >> 6, ww = rem & 63;
    int win = (bb * 5 + h / 14) * 5 + ww / 14;
    int t = (h % 14) * 14 + (ww % 14);
    dst = out + ((size_t)win * 196 + t) * 768;
  } else {
    dst = out + (size_t)blk * 768;
  }
  dst[tid] = f2bf((v0 - mu) * sc * w[tid] + b[tid]);
  dst[tid + 256] = f2bf((v1 - mu) * sc * w[tid + 256] + b[tid + 256]);
  dst[tid + 512] = f2bf((v2 - mu) * sc * w[tid + 512] + b[tid + 512]);
}

// ---------------------------------------------------------------------------
// bf16 GEMM: C[M][N] = A[M][K] @ Bt[N][K]^T (+ epilogue)
// 128x128 block tile, BK=32, 4 waves in 2x2, each wave 64x64 as 2x2 tiles of
// 32x32 (MFMA 32x32x16, acc f32x16[2][2]). Per iter per wave: 8 ds_read_b128
// + 8 MFMA (vs 16 at 16x16 shape) -- fatter ops, higher pipe rate, shorter
// dependent chain.
// Schedule = R3-verified 2-phase: explicit LDS double-buffer (2 x 16KB),
// STAGE(next) issued first (global_load_lds DMA), compute on current buffer,
// one s_waitcnt vmcnt(0) + s_barrier per tile.
// LDS tile layout [128 rows][4 chunks of 16B], swizzled:
//   slot = chunk ^ (row&3) ^ (((row>>2)&1)<<1)   (R3: 0 conflicts)
// DMA dest stays linear (tid*16B); the global SOURCE is inverse-permuted.
// Fragment mapping (gfx950 2xK pattern): A row=lane&31, k=(lane>>5)*8+j per
// K=16 half; C/D col=lane&31, row=(reg&3)+8*(reg>>2)+4*(lane>>5) [m74/m101].
// EPI: 0=+bias->bf16 (qkv), 1=+bias+resid, window-unpartition ->fp32 d_out
//      2=+bias,gelu->bf16 (mlp1), 3=+bias, d_out += (mlp2)
// ---------------------------------------------------------------------------
template <int EPI>
__global__ __launch_bounds__(256, 2) void gemm_bt(
    const unsigned short* __restrict__ A, const unsigned short* __restrict__ Bt,
    const float* __restrict__ bias, int M, int N, int K,
    unsigned short* __restrict__ obf, float* __restrict__ of,
    const float* __restrict__ resid) {
  __shared__ __align__(16) unsigned short smem[2][8192];  // [buf][A:0..4096|B:4096..8192]
  const int tid = threadIdx.x;
  const int lane = tid & 63, wv = tid >> 6;
  const int ln31 = lane & 31, hi = lane >> 5;
  const int wm = wv & 1, wn = wv >> 1;

  // bijective XCD-chunked swizzle (8 XCDs)
  int bid = blockIdx.y * gridDim.x + blockIdx.x;
  {
    const int nwg = gridDim.x * gridDim.y;
    const int qq = nwg >> 3, rr = nwg & 7;
    const int xcd = bid & 7, lo = bid >> 3;
    bid = (xcd < rr ? xcd * (qq + 1) : rr * (qq + 1) + (xcd - rr) * qq) + lo;
  }
  const int m0 = (bid / gridDim.x) * 128, n0 = (bid % gridDim.x) * 128;

  // staging: thread t covers (row = q*64 + t>>2, slot = t&3) for q=0,1 in each
  // of A,B. LDS linear index = q*2048 + t*8 (wave-uniform base + lane*16B).
  // Source chunk for slot s of row r is s ^ (r&3) ^ (((r>>2)&1)<<1):
  const int rr_ = tid >> 2;
  const int csrc =
      (((tid & 3) ^ ((tid >> 2) & 3) ^ (((tid >> 4) & 1) << 1)) << 3);
  const unsigned short* pA0 = A + (size_t)min(m0 + rr_, M - 1) * K + csrc;
  const unsigned short* pA1 = A + (size_t)min(m0 + 64 + rr_, M - 1) * K + csrc;
  const unsigned short* pB0 = Bt + (size_t)(n0 + rr_) * K + csrc;
  const unsigned short* pB1 = Bt + (size_t)(n0 + 64 + rr_) * K + csrc;

  // ds_read: lane (ln31,hi) wants, for k-half kh, global chunk kh*2+hi of row
  // (tile*32 + ln31). Row term: (32*tile)&7==0 so slot depends only on ln31:
  int slotk[2];
#pragma unroll
  for (int kh = 0; kh < 2; kh++)
    slotk[kh] =
        (((kh * 2 + hi) ^ (ln31 & 3) ^ (((ln31 >> 2) & 1) << 1)) << 3);

  f32x16 acc[2][2];
#pragma unroll
  for (int i = 0; i < 2; i++)
#pragma unroll
    for (int j = 0; j < 2; j++)
#pragma unroll
      for (int e = 0; e < 16; e++) acc[i][j][e] = 0.f;

#define STAGE(BUF, KT)                                                        \
  do {                                                                        \
    unsigned short* d_ = &smem[BUF][0] + tid * 8;                             \
    gload_lds16(pA0 + (KT), d_);                                              \
    gload_lds16(pA1 + (KT), d_ + 2048);                                      \
    gload_lds16(pB0 + (KT), d_ + 4096);                                      \
    gload_lds16(pB1 + (KT), d_ + 6144);                                      \
  } while (0)

  // prologue: stage tile 0, drain, barrier
  STAGE(0, 0);
  asm volatile("s_waitcnt vmcnt(0)" ::: "memory");
  __builtin_amdgcn_sched_barrier(0);
  __builtin_amdgcn_s_barrier();

  int cur = 0;
  for (int kt = 0; kt < K; kt += 32) {
    const bool more = (kt + 32 < K);
    if (more) STAGE(cur ^ 1, kt + 32);  // issue next-tile DMA before compute
    const unsigned short* cb = &smem[cur][0];
    bf16x8 af[2][2], bv[2][2];
#pragma unroll
    for (int ti = 0; ti < 2; ti++)
#pragma unroll
      for (int kh = 0; kh < 2; kh++)
        af[ti][kh] = ld8(cb + (wm * 64 + ti * 32 + ln31) * 32 + slotk[kh]);
#pragma unroll
    for (int tj = 0; tj < 2; tj++)
#pragma unroll
      for (int kh = 0; kh < 2; kh++)
        bv[tj][kh] =
            ld8(cb + 4096 + (wn * 64 + tj * 32 + ln31) * 32 + slotk[kh]);
#pragma unroll
    for (int kh = 0; kh < 2; kh++)
#pragma unroll
      for (int ti = 0; ti < 2; ti++)
#pragma unroll
        for (int tj = 0; tj < 2; tj++)
          acc[ti][tj] = __builtin_amdgcn_mfma_f32_32x32x16_bf16(
              af[ti][kh], bv[tj][kh], acc[ti][tj], 0, 0, 0);
    if (more) {
      asm volatile("s_waitcnt vmcnt(0)" ::: "memory");  // next tile landed
      __builtin_amdgcn_sched_barrier(0);
      __builtin_amdgcn_s_barrier();
    }
    cur ^= 1;
  }
#undef STAGE

  // Epilogue. C/D 32x32 layout: col = lane&31,
  // row = (reg&3) + 8*(reg>>2) + 4*(lane>>5)   [verified m74/m101].
#pragma unroll
  for (int ti = 0; ti < 2; ti++) {
#pragma unroll
    for (int tj = 0; tj < 2; tj++) {
      const int col = n0 + wn * 64 + tj * 32 + ln31;
      const float bc = bias[col];
#pragma unroll
      for (int reg = 0; reg < 16; reg++) {
        const int row =
            m0 + wm * 64 + ti * 32 + (reg & 3) + ((reg >> 2) << 3) + (hi << 2);
        if (row >= M) continue;
        float v = acc[ti][tj][reg] + bc;
        if constexpr (EPI == 0) {
          obf[(size_t)row * N + col] = f2bf(v);
        } else if constexpr (EPI == 2) {
          float gl = 0.5f * v * (1.0f + erff(v * 0.70710678118f));
          obf[(size_t)row * N + col] = f2bf(gl);
        } else if constexpr (EPI == 1) {
          // row -> (b,h,w) via window unpartition; drop padded positions
          int win = row / 196, t = row - win * 196;
          int b = win / 25, wg = win - b * 25;
          int wr = wg / 5, wc = wg - wr * 5;
          int h = wr * 14 + t / 14;
          int w = wc * 14 + (t % 14);
          if (h < 64 && w < 64) {
            size_t oi = (((size_t)(b * 64 + h)) * 64 + w) * 768 + col;
            of[oi] = v + resid[oi];
          }
        } else {  // EPI == 3
          size_t oi = (size_t)row * N + col;
          of[oi] += v;
        }
      }
    }
  }
}

// ---------------------------------------------------------------------------
// Fused windowed attention: one block per (window, head). 2400 blocks.
// qkv: bf16 [200*196][2304]; q cols h*64.., k cols 768+h*64.., v 1536+h*64..
// S = (Q Kt)*0.125 + Sh[qr,kr] + Sw[qc,kc]; softmax; O = P V.
// Q/K fragments read directly from global (L1-resident); V transposed in LDS;
// P strip round-trips LDS per wave (C-layout -> A-layout).
// ---------------------------------------------------------------------------
__global__ __launch_bounds__(256, 2) void attn_kernel(
    const unsigned short* __restrict__ qkv, const int* __restrict__ q_idx,
    const int* __restrict__ k_idx, const float* __restrict__ shsw,
    unsigned short* __restrict__ attnout) {
  __shared__ __align__(16) unsigned short Vt[64][232];   // [channel][key] pad->2-way banks
  __shared__ __align__(16) unsigned short Pst[4][16 * 232];  // per-wave P strip
  __shared__ float Shs[196], Sws[196];
  __shared__ short qr14a[208], qc14a[208], kra[208], kca[208];

  const int tid = threadIdx.x;
  const int blk = blockIdx.x;
  const int win = blk / 12, head = blk % 12;
  const int lane = tid & 63, wv = tid >> 6;
  const int ln15 = lane & 15, quad = lane >> 4;
  const unsigned short* qg = qkv + (size_t)win * 196 * 2304;

  // zero Vt & Pst (covers key/col padding 196..223 and strip cols 208..223)
  {
    unsigned int* vz = (unsigned int*)&Vt[0][0];
    for (int i = tid; i < 64 * 232 / 2; i += 256) vz[i] = 0u;
    unsigned int* pz = (unsigned int*)&Pst[0][0];
    for (int i = tid; i < 4 * 16 * 232 / 2; i += 256) pz[i] = 0u;
  }
  // V -> Vt transposed
  for (int i = tid; i < 196 * 64; i += 256) {
    int r = i >> 6, c = i & 63;
    Vt[c][r] = qg[(size_t)r * 2304 + 1536 + head * 64 + c];
  }
  // bias tables + index arrays
  for (int i = tid; i < 208; i += 256) {
    if (i < 196) {
      Shs[i] = shsw[i];
      Sws[i] = shsw[196 + i];
    }
    int q = (i < 196) ? q_idx[(size_t)blk * 196 + i] : 0;
    int k = (i < 196) ? k_idx[(size_t)blk * 196 + i] : 0;
    qr14a[i] = (short)((q / 14) * 14);
    qc14a[i] = (short)((q % 14) * 14);
    kra[i] = (short)(k / 14);
    kca[i] = (short)(k % 14);
  }
  __syncthreads();

  const f32x4 fz = {0.f, 0.f, 0.f, 0.f};
  unsigned short* strip = &Pst[wv][0];

  for (int mt = wv; mt < 13; mt += 4) {
    // ---- Q fragments (A-layout: m=lane&15, k=quad*8+j) from global ----
    int qrow = mt * 16 + ln15;
    int qrc = (qrow < 196) ? qrow : 0;
    const unsigned short* qrp = qg + (size_t)qrc * 2304 + head * 64 + quad * 8;
    bf16x8 aq0 = ld8(qrp);
    bf16x8 aq1 = ld8(qrp + 32);

    // ---- S = Q K^T over 13 col tiles ----
    f32x4 sacc[13];
#pragma unroll
    for (int nt = 0; nt < 13; nt++) {
      sacc[nt] = fz;
      int krow = nt * 16 + ln15;
      if (krow > 195) krow = 0;
      const unsigned short* krp =
          qg + (size_t)krow * 2304 + 768 + head * 64 + quad * 8;
      bf16x8 bk0 = ld8(krp);
      bf16x8 bk1 = ld8(krp + 32);
      sacc[nt] = __builtin_amdgcn_mfma_f32_16x16x32_bf16(aq0, bk0, sacc[nt], 0, 0, 0);
      sacc[nt] = __builtin_amdgcn_mfma_f32_16x16x32_bf16(aq1, bk1, sacc[nt], 0, 0, 0);
    }

    // ---- softmax (rows = quad*4+g of this mt tile) ----
    const int r0 = mt * 16 + quad * 4;
    int qi[4], qci[4];
#pragma unroll
    for (int g = 0; g < 4; g++) {
      qi[g] = qr14a[r0 + g];
      qci[g] = qc14a[r0 + g];
    }
    float rmax[4] = {-1e30f, -1e30f, -1e30f, -1e30f};
#pragma unroll
    for (int nt = 0; nt < 13; nt++) {
      int col = nt * 16 + ln15;
      int kr_ = kra[col], kc_ = kca[col];
#pragma unroll
      for (int g = 0; g < 4; g++) {
        float v = sacc[nt][g] * 0.125f + Shs[qi[g] + kr_] + Sws[qci[g] + kc_];
        if (col >= 196) v = -1e30f;
        sacc[nt][g] = v;
        rmax[g] = fmaxf(rmax[g], v);
      }
    }
#pragma unroll
    for (int off = 1; off < 16; off <<= 1)
#pragma unroll
      for (int g = 0; g < 4; g++)
        rmax[g] = fmaxf(rmax[g], __shfl_xor(rmax[g], off, 16));
    float rsum[4] = {0.f, 0.f, 0.f, 0.f};
#pragma unroll
    for (int nt = 0; nt < 13; nt++) {
      int col = nt * 16 + ln15;
#pragma unroll
      for (int g = 0; g < 4; g++) {
        float p = (col >= 196) ? 0.f : __expf(sacc[nt][g] - rmax[g]);
        sacc[nt][g] = p;
        rsum[g] += p;
      }
    }
#pragma unroll
    for (int off = 1; off < 16; off <<= 1)
#pragma unroll
      for (int g = 0; g < 4; g++) rsum[g] += __shfl_xor(rsum[g], off, 16);
    float rinv[4];
#pragma unroll
    for (int g = 0; g < 4; g++) rinv[g] = 1.0f / rsum[g];

    // ---- write P strip (row-major [16][232] bf16, A-layout source for PV) ----
#pragma unroll
    for (int nt = 0; nt < 13; nt++) {
      int col = nt * 16 + ln15;
#pragma unroll
      for (int g = 0; g < 4; g++)
        strip[(quad * 4 + g) * 232 + col] = f2bf(sacc[nt][g] * rinv[g]);
    }

    // ---- O = P V  (K padded to 224; strip/Vt zeros beyond 196) ----
    f32x4 oacc[4];
#pragma unroll
    for (int c4 = 0; c4 < 4; c4++) oacc[c4] = fz;
#pragma unroll
    for (int ks = 0; ks < 7; ks++) {
      bf16x8 ap = ld8(strip + ln15 * 232 + ks * 32 + quad * 8);
#pragma unroll
      for (int c4 = 0; c4 < 4; c4++) {
        bf16x8 bvv = ld8(&Vt[c4 * 16 + ln15][ks * 32 + quad * 8]);
        oacc[c4] = __builtin_amdgcn_mfma_f32_16x16x32_bf16(ap, bvv, oacc[c4], 0, 0, 0);
      }
    }
    // ---- store (C-layout: col=lane&15 channel, row=quad*4+g token) ----
#pragma unroll
    for (int c4 = 0; c4 < 4; c4++)
#pragma unroll
      for (int g = 0; g < 4; g++) {
        int row = r0 + g;
        if (row < 196)
          attnout[((size_t)win * 196 + row) * 768 + head * 64 + c4 * 16 + ln15] =
              f2bf(oacc[c4][g]);
      }
  }
}

// ---------------------------------------------------------------------------
// Launch. Workspace layout (bytes):
//   [0, 60211200)              region A: xw bf16 [39200][768] -> attnout -> ln2
//   [60211200, 261537792)      region B: qkv bf16 [39200][2304] -> mlp1 [32768][3072]
//   [261537792, ...)           transposed weights bf16 + ShSw tables (~14.2 MB)
// Peak ws use ~276 MB.
// ---------------------------------------------------------------------------
extern "C" void kernel_launch(void* const* d_in, const int* in_sizes, int n_in,
                              void* d_out, int out_size, void* d_ws,
                              size_t ws_size, hipStream_t stream) {
  const float* x = (const float*)d_in[0];
  const int* q_idx = (const int*)d_in[1];
  const int* k_idx = (const int*)d_in[2];
  const float* ln1w = (const float*)d_in[3];
  const float* ln1b = (const float*)d_in[4];
  const float* ln2w = (const float*)d_in[5];
  const float* ln2b = (const float*)d_in[6];
  const float* qkvw = (const float*)d_in[7];
  const float* qkvb = (const float*)d_in[8];
  const float* projw = (const float*)d_in[9];
  const float* projb = (const float*)d_in[10];
  const float* relh = (const float*)d_in[11];
  const float* relw = (const float*)d_in[12];
  const float* w1 = (const float*)d_in[13];
  const float* b1 = (const float*)d_in[14];
  const float* w2 = (const float*)d_in[15];
  const float* b2 = (const float*)d_in[16];
  float* out = (float*)d_out;

  char* ws = (char*)d_ws;
  unsigned short* xw = (unsigned short*)ws;  // region A
  const size_t offA = 60211200;              // 39200*768*2
  unsigned short* qkv = (unsigned short*)(ws + offA);  // region B
  const size_t offB = offA + 201326592;      // max(qkv, mlp1)
  unsigned short* qkvwt = (unsigned short*)(ws + offB);
  unsigned short* projwt = qkvwt + 2304 * 768;
  unsigned short* w1t = projwt + 768 * 768;
  unsigned short* w2t = w1t + 3072 * 768;
  float* shsw = (float*)(w2t + 768 * 3072);

  unsigned short* attnout = xw;  // region A reuse (xw dead after qkv GEMM)
  unsigned short* ln2buf = xw;   // region A reuse (attnout dead after proj)
  unsigned short* mlp1 = qkv;    // region B reuse (qkv dead after attention)

  // zero xw so spatially-padded window tokens are zero feature vectors
  hipMemsetAsync(xw, 0, (size_t)39200 * 768 * 2, stream);

  dim3 tb(32, 8);
  transpose_w<<<dim3(2304 / 32, 768 / 32), tb, 0, stream>>>(qkvw, qkvwt, 768, 2304);
  transpose_w<<<dim3(768 / 32, 768 / 32), tb, 0, stream>>>(projw, projwt, 768, 768);
  transpose_w<<<dim3(3072 / 32, 768 / 32), tb, 0, stream>>>(w1, w1t, 768, 3072);
  transpose_w<<<dim3(768 / 32, 3072 / 32), tb, 0, stream>>>(w2, w2t, 3072, 768);
  shsw_kernel<<<1, 256, 0, stream>>>(relh, relw, shsw);

  // LN1 + window partition -> bf16
  ln_kernel<<<32768, 256, 0, stream>>>(x, ln1w, ln1b, xw, 1);

  // qkv = xw @ qkv_w + b   [39200,768]x[768,2304]
  gemm_bt<0><<<dim3(18, 307), 256, 0, stream>>>(xw, qkvwt, qkvb, 39200, 2304,
                                                768, qkv, nullptr, nullptr);
  // fused windowed attention
  attn_kernel<<<2400, 256, 0, stream>>>(qkv, q_idx, k_idx, shsw, attnout);

  // proj + residual + unpartition -> d_out (fp32 x_mid)
  gemm_bt<1><<<dim3(6, 307), 256, 0, stream>>>(attnout, projwt, projb, 39200,
                                               768, 768, nullptr, out, x);
  // LN2 -> bf16
  ln_kernel<<<32768, 256, 0, stream>>>(out, ln2w, ln2b, ln2buf, 0);

  // mlp1 = gelu(ln2 @ w1 + b1)   [32768,768]x[768,3072]
  gemm_bt<2><<<dim3(24, 256), 256, 0, stream>>>(ln2buf, w1t, b1, 32768, 3072,
                                                768, mlp1, nullptr, nullptr);
  // d_out += mlp1 @ w2 + b2      [32768,3072]x[3072,768]
  gemm_bt<3><<<dim3(6, 256), 256, 0, stream>>>(mlp1, w2t, b2, 32768, 768, 3072,
                                               nullptr, out, nullptr);
  (void)in_sizes; (void)n_in; (void)out_size; (void)ws_size;
}

// Round 8
// 1270.537 us; speedup vs baseline: 1.1549x; 1.0481x over previous
//
#include <hip/hip_runtime.h>

// ---------------------------------------------------------------------------
// SAM windowed-attention block, bf16-MFMA implementation.
// B=8 H=W=64 DIM=768 NH=12 HD=64 WS=14 N=196 PAD=6 -> 70x70, 5x5=25 windows,
// Bp=200 windows, 2400 (window,head) pairs. GEMMs bf16 MFMA 16x16x32, fp32
// accumulate. Softmax/LN/gelu in fp32.
// R8: GEMM frozen at R3 (best of 6 probes: 288us, 0 conflicts; 8-phase/256^2/
// 32x32-shape all regressed -> 2-barrier family ceiling for these shapes).
// This round: non-GEMM time. (1) attn V-transpose loads vectorized bf16x8,
// (2) attn LDS zeroing shrunk to the actually-read zero tails (16x fewer
// stores), (3) LayerNorm rebuilt at 192 thr with float4 loads + short4
// bf16 stores (was 3 scalar loads + 3 scalar 2B stores per thread).
// ---------------------------------------------------------------------------

typedef __bf16 bf16x8 __attribute__((ext_vector_type(8)));
typedef float f32x4 __attribute__((ext_vector_type(4)));
typedef unsigned int u32x4 __attribute__((ext_vector_type(4)));
typedef unsigned short u16x4 __attribute__((ext_vector_type(4)));

__device__ __forceinline__ unsigned short f2bf(float f) {
  unsigned int u = __builtin_bit_cast(unsigned int, f);
  u += 0x7FFFu + ((u >> 16) & 1u);
  return (unsigned short)(u >> 16);
}

__device__ __forceinline__ bf16x8 ld8(const unsigned short* p) {
  return __builtin_bit_cast(bf16x8, *(const u32x4*)p);
}

// async global->LDS, 16B per lane. LDS dest must be wave-uniform base + lane*16.
__device__ __forceinline__ void gload_lds16(const unsigned short* g,
                                            unsigned short* l) {
  __builtin_amdgcn_global_load_lds(
      (const __attribute__((address_space(1))) unsigned int*)g,
      (__attribute__((address_space(3))) unsigned int*)l, 16, 0, 0);
}

// ---------------------------------------------------------------------------
// Weight transpose fp32[K][N] -> bf16[N][K]  (all dims multiples of 32)
// ---------------------------------------------------------------------------
__global__ void transpose_w(const float* __restrict__ in,
                            unsigned short* __restrict__ out, int K, int N) {
  __shared__ float t[32][33];
  int n = blockIdx.x * 32 + threadIdx.x;
  int kb = blockIdx.y * 32;
#pragma unroll
  for (int i = 0; i < 4; i++) {
    int k = kb + threadIdx.y + i * 8;
    t[threadIdx.y + i * 8][threadIdx.x] = in[(size_t)k * N + n];
  }
  __syncthreads();
  int k2 = kb + threadIdx.x;
#pragma unroll
  for (int i = 0; i < 4; i++) {
    int n2 = blockIdx.x * 32 + threadIdx.y + i * 8;
    out[(size_t)n2 * K + k2] = f2bf(t[threadIdx.x][threadIdx.y + i * 8]);
  }
}

// ---------------------------------------------------------------------------
// Rel-pos tables: Sh[i*14+j] = sum_c rel_h[(i-j+13)*64+c]; same for Sw.
// out layout: [0..195]=Sh, [196..391]=Sw
// ---------------------------------------------------------------------------
__global__ void shsw_kernel(const float* __restrict__ rh,
                            const float* __restrict__ rw,
                            float* __restrict__ o) {
  int t = threadIdx.x;
  if (t < 196) {
    int i = t / 14, j = t % 14, d = i - j + 13;
    float sh = 0.f, sw = 0.f;
    for (int c = 0; c < 64; c++) {
      sh += rh[d * 64 + c];
      sw += rw[d * 64 + c];
    }
    o[t] = sh;
    o[196 + t] = sw;
  }
}

// ---------------------------------------------------------------------------
// LayerNorm over 768. 192 threads: thread t owns cols 4t..4t+3 (float4 load,
// short4 bf16 store -> 16B/8B per lane vs old 4B/2B scalars).
// windowed=1: write to window-partitioned layout [win*196+t][768];
// windowed=0: write [row][768]. Output bf16.
// ---------------------------------------------------------------------------
__global__ __launch_bounds__(192) void ln_kernel(
    const float* __restrict__ xin, const float* __restrict__ w,
    const float* __restrict__ b, unsigned short* __restrict__ out,
    int windowed) {
  __shared__ float red[6];
  __shared__ float ms[2];
  const int tid = threadIdx.x;
  const int blk = blockIdx.x;
  const float4 v = ((const float4*)(xin + (size_t)blk * 768))[tid];
  float s = v.x + v.y + v.z + v.w;
  float q = v.x * v.x + v.y * v.y + v.z * v.z + v.w * v.w;
#pragma unroll
  for (int off = 32; off > 0; off >>= 1) {
    s += __shfl_down(s, off, 64);
    q += __shfl_down(q, off, 64);
  }
  const int wv = tid >> 6, lane = tid & 63;
  if (lane == 0) { red[wv] = s; red[3 + wv] = q; }
  __syncthreads();
  if (tid == 0) {
    float st = red[0] + red[1] + red[2];
    float qt = red[3] + red[4] + red[5];
    float mu = st * (1.0f / 768.0f);
    float var = qt * (1.0f / 768.0f) - mu * mu;
    ms[0] = mu;
    ms[1] = rsqrtf(var + 1e-5f);
  }
  __syncthreads();
  const float mu = ms[0], sc = ms[1];
  const float4 w4 = ((const float4*)w)[tid];
  const float4 b4 = ((const float4*)b)[tid];
  u16x4 o;
  o[0] = f2bf((v.x - mu) * sc * w4.x + b4.x);
  o[1] = f2bf((v.y - mu) * sc * w4.y + b4.y);
  o[2] = f2bf((v.z - mu) * sc * w4.z + b4.z);
  o[3] = f2bf((v.w - mu) * sc * w4.w + b4.w);
  unsigned short* dst;
  if (windowed) {
    int bb = blk >> 12, rem = blk & 4095, h = rem >> 6, ww = rem & 63;
    int win = (bb * 5 + h / 14) * 5 + ww / 14;
    int t = (h % 14) * 14 + (ww % 14);
    dst = out + ((size_t)win * 196 + t) * 768;
  } else {
    dst = out + (size_t)blk * 768;
  }
  ((u16x4*)dst)[tid] = o;
}

// ---------------------------------------------------------------------------
// bf16 GEMM: C[M][N] = A[M][K] @ Bt[N][K]^T (+ epilogue)  [R3-frozen]
// 128x128 block tile, BK=32, 4 waves in 2x2, each wave 64x64 (4x4 MFMA tiles).
// Explicit LDS double-buffer (2 x 16KB): STAGE(next) issued first
// (global_load_lds DMA), compute on current buffer, one s_waitcnt vmcnt(0) +
// s_barrier per tile. 32KB LDS -> 3-4 blocks/CU TLP.
// LDS tile layout [128 rows][4 chunks of 16B], swizzled:
//   slot = chunk ^ (row&3) ^ (((row>>2)&1)<<1)   (verified: 0 conflicts)
// DMA dest stays linear (tid*16B); the global SOURCE is inverse-permuted.
// EPI: 0=+bias->bf16 (qkv), 1=+bias+resid, window-unpartition ->fp32 d_out
//      2=+bias,gelu->bf16 (mlp1), 3=+bias, d_out += (mlp2)
// ---------------------------------------------------------------------------
template <int EPI>
__global__ __launch_bounds__(256, 2) void gemm_bt(
    const unsigned short* __restrict__ A, const unsigned short* __restrict__ Bt,
    const float* __restrict__ bias, int M, int N, int K,
    unsigned short* __restrict__ obf, float* __restrict__ of,
    const float* __restrict__ resid) {
  __shared__ __align__(16) unsigned short smem[2][8192];  // [buf][A:0..4096|B:4096..8192]
  const int tid = threadIdx.x;
  const int lane = tid & 63, wv = tid >> 6;
  const int ln15 = lane & 15, quad = lane >> 4;
  const int wm = wv & 1, wn = wv >> 1;

  // bijective XCD-chunked swizzle (8 XCDs)
  int bid = blockIdx.y * gridDim.x + blockIdx.x;
  {
    const int nwg = gridDim.x * gridDim.y;
    const int qq = nwg >> 3, rr = nwg & 7;
    const int xcd = bid & 7, lo = bid >> 3;
    bid = (xcd < rr ? xcd * (qq + 1) : rr * (qq + 1) + (xcd - rr) * qq) + lo;
  }
  const int m0 = (bid / gridDim.x) * 128, n0 = (bid % gridDim.x) * 128;

  // staging: thread t covers (row = q*64 + t>>2, slot = t&3) for q=0,1 in each
  // of A,B. LDS linear index = q*2048 + t*8 (wave-uniform base + lane*16B).
  // Source chunk for slot s of row r is s ^ (r&3) ^ (((r>>2)&1)<<1):
  const int rr_ = tid >> 2;
  const int csrc =
      (((tid & 3) ^ ((tid >> 2) & 3) ^ (((tid >> 4) & 1) << 1)) << 3);
  const unsigned short* pA0 = A + (size_t)min(m0 + rr_, M - 1) * K + csrc;
  const unsigned short* pA1 = A + (size_t)min(m0 + 64 + rr_, M - 1) * K + csrc;
  const unsigned short* pB0 = Bt + (size_t)(n0 + rr_) * K + csrc;
  const unsigned short* pB1 = Bt + (size_t)(n0 + 64 + rr_) * K + csrc;

  // ds_read: lane (ln15,quad) wants global chunk=quad of row (..+ln15):
  const int rslot =
      ((quad ^ (ln15 & 3) ^ (((ln15 >> 2) & 1) << 1)) << 3);

  const f32x4 fz = {0.f, 0.f, 0.f, 0.f};
  f32x4 acc[4][4];
#pragma unroll
  for (int i = 0; i < 4; i++)
#pragma unroll
    for (int j = 0; j < 4; j++) acc[i][j] = fz;

#define STAGE(BUF, KT)                                                        \
  do {                                                                        \
    unsigned short* d_ = &smem[BUF][0] + tid * 8;                             \
    gload_lds16(pA0 + (KT), d_);                                              \
    gload_lds16(pA1 + (KT), d_ + 2048);                                       \
    gload_lds16(pB0 + (KT), d_ + 4096);                                       \
    gload_lds16(pB1 + (KT), d_ + 6144);                                       \
  } while (0)

  // prologue: stage tile 0, drain, barrier
  STAGE(0, 0);
  asm volatile("s_waitcnt vmcnt(0)" ::: "memory");
  __builtin_amdgcn_sched_barrier(0);
  __builtin_amdgcn_s_barrier();

  int cur = 0;
  for (int kt = 0; kt < K; kt += 32) {
    const bool more = (kt + 32 < K);
    if (more) STAGE(cur ^ 1, kt + 32);  // issue next-tile DMA before compute
    bf16x8 af[4], bv[4];
    const unsigned short* cb = &smem[cur][0];
#pragma unroll
    for (int t = 0; t < 4; t++) {
      af[t] = ld8(cb + (wm * 64 + t * 16 + ln15) * 32 + rslot);
      bv[t] = ld8(cb + 4096 + (wn * 64 + t * 16 + ln15) * 32 + rslot);
    }
#pragma unroll
    for (int i = 0; i < 4; i++)
#pragma unroll
      for (int j = 0; j < 4; j++)
        acc[i][j] =
            __builtin_amdgcn_mfma_f32_16x16x32_bf16(af[i], bv[j], acc[i][j], 0, 0, 0);
    if (more) {
      asm volatile("s_waitcnt vmcnt(0)" ::: "memory");  // next tile landed
      __builtin_amdgcn_sched_barrier(0);
      __builtin_amdgcn_s_barrier();
    }
    cur ^= 1;
  }
#undef STAGE

  // Epilogue. C/D layout: col = lane&15, row = quad*4 + reg (verified m89/m91).
#pragma unroll
  for (int i = 0; i < 4; i++) {
#pragma unroll
    for (int j = 0; j < 4; j++) {
      const int col = n0 + wn * 64 + j * 16 + ln15;
      const float bc = bias[col];
#pragma unroll
      for (int g = 0; g < 4; g++) {
        const int row = m0 + wm * 64 + i * 16 + quad * 4 + g;
        if (row >= M) continue;
        float v = acc[i][j][g] + bc;
        if constexpr (EPI == 0) {
          obf[(size_t)row * N + col] = f2bf(v);
        } else if constexpr (EPI == 2) {
          float gl = 0.5f * v * (1.0f + erff(v * 0.70710678118f));
          obf[(size_t)row * N + col] = f2bf(gl);
        } else if constexpr (EPI == 1) {
          // row -> (b,h,w) via window unpartition; drop padded positions
          int win = row / 196, t = row - win * 196;
          int b = win / 25, wg = win - b * 25;
          int wr = wg / 5, wc = wg - wr * 5;
          int h = wr * 14 + t / 14;
          int w = wc * 14 + (t % 14);
          if (h < 64 && w < 64) {
            size_t oi = (((size_t)(b * 64 + h)) * 64 + w) * 768 + col;
            of[oi] = v + resid[oi];
          }
        } else {  // EPI == 3
          size_t oi = (size_t)row * N + col;
          of[oi] += v;
        }
      }
    }
  }
}

// ---------------------------------------------------------------------------
// Fused windowed attention: one block per (window, head). 2400 blocks.
// qkv: bf16 [200*196][2304]; q cols h*64.., k cols 768+h*64.., v 1536+h*64..
// S = (Q Kt)*0.125 + Sh[qr,kr] + Sw[qc,kc]; softmax; O = P V.
// Q/K fragments read directly from global (L1-resident); V transposed in LDS
// (vectorized bf16x8 row loads -> scalar scatter writes); P strip round-trips
// LDS per wave (C-layout -> A-layout). Zero-fill only the read tails:
// Vt cols 196..231, Pst cols 208..231 (all other cells are written before
// their first read).
// ---------------------------------------------------------------------------
__global__ __launch_bounds__(256, 2) void attn_kernel(
    const unsigned short* __restrict__ qkv, const int* __restrict__ q_idx,
    const int* __restrict__ k_idx, const float* __restrict__ shsw,
    unsigned short* __restrict__ attnout) {
  __shared__ __align__(16) unsigned short Vt[64][232];   // [channel][key] pad->2-way banks
  __shared__ __align__(16) unsigned short Pst[4][16 * 232];  // per-wave P strip
  __shared__ float Shs[196], Sws[196];
  __shared__ short qr14a[208], qc14a[208], kra[208], kca[208];

  const int tid = threadIdx.x;
  const int blk = blockIdx.x;
  const int win = blk / 12, head = blk % 12;
  const int lane = tid & 63, wv = tid >> 6;
  const int ln15 = lane & 15, quad = lane >> 4;
  const unsigned short* qg = qkv + (size_t)win * 196 * 2304;

  // zero ONLY the read-but-never-written tails (u32 stores):
  // Vt cols 196..231 (PV reads keys up to 223), all 64 channels: 64x18 u32.
  for (int i = tid; i < 64 * 18; i += 256) {
    int c = i / 18, j = i - c * 18;
    *(unsigned int*)&Vt[c][196 + 2 * j] = 0u;
  }
  // Pst cols 208..231 of each 16-row strip (PV reads cols up to 223): 4x16x12.
  for (int i = tid; i < 4 * 16 * 12; i += 256) {
    int s0 = i / 192, rem = i - s0 * 192;
    int r = rem / 12, j = rem - r * 12;
    *(unsigned int*)&Pst[s0][r * 232 + 208 + 2 * j] = 0u;
  }
  // V -> Vt transposed: vectorized row loads (bf16x8), scatter scalar writes.
  for (int i = tid; i < 196 * 8; i += 256) {
    int r = i >> 3, cb = (i & 7) << 3;
    const u32x4 vvv =
        *(const u32x4*)(qg + (size_t)r * 2304 + 1536 + head * 64 + cb);
#pragma unroll
    for (int j = 0; j < 4; j++) {
      unsigned int wrd = vvv[j];
      Vt[cb + 2 * j][r] = (unsigned short)(wrd & 0xffffu);
      Vt[cb + 2 * j + 1][r] = (unsigned short)(wrd >> 16);
    }
  }
  // bias tables + index arrays
  for (int i = tid; i < 208; i += 256) {
    if (i < 196) {
      Shs[i] = shsw[i];
      Sws[i] = shsw[196 + i];
    }
    int q = (i < 196) ? q_idx[(size_t)blk * 196 + i] : 0;
    int k = (i < 196) ? k_idx[(size_t)blk * 196 + i] : 0;
    qr14a[i] = (short)((q / 14) * 14);
    qc14a[i] = (short)((q % 14) * 14);
    kra[i] = (short)(k / 14);
    kca[i] = (short)(k % 14);
  }
  __syncthreads();

  const f32x4 fz = {0.f, 0.f, 0.f, 0.f};
  unsigned short* strip = &Pst[wv][0];

  for (int mt = wv; mt < 13; mt += 4) {
    // ---- Q fragments (A-layout: m=lane&15, k=quad*8+j) from global ----
    int qrow = mt * 16 + ln15;
    int qrc = (qrow < 196) ? qrow : 0;
    const unsigned short* qrp = qg + (size_t)qrc * 2304 + head * 64 + quad * 8;
    bf16x8 aq0 = ld8(qrp);
    bf16x8 aq1 = ld8(qrp + 32);

    // ---- S = Q K^T over 13 col tiles ----
    f32x4 sacc[13];
#pragma unroll
    for (int nt = 0; nt < 13; nt++) {
      sacc[nt] = fz;
      int krow = nt * 16 + ln15;
      if (krow > 195) krow = 0;
      const unsigned short* krp =
          qg + (size_t)krow * 2304 + 768 + head * 64 + quad * 8;
      bf16x8 bk0 = ld8(krp);
      bf16x8 bk1 = ld8(krp + 32);
      sacc[nt] = __builtin_amdgcn_mfma_f32_16x16x32_bf16(aq0, bk0, sacc[nt], 0, 0, 0);
      sacc[nt] = __builtin_amdgcn_mfma_f32_16x16x32_bf16(aq1, bk1, sacc[nt], 0, 0, 0);
    }

    // ---- softmax (rows = quad*4+g of this mt tile) ----
    const int r0 = mt * 16 + quad * 4;
    int qi[4], qci[4];
#pragma unroll
    for (int g = 0; g < 4; g++) {
      qi[g] = qr14a[r0 + g];
      qci[g] = qc14a[r0 + g];
    }
    float rmax[4] = {-1e30f, -1e30f, -1e30f, -1e30f};
#pragma unroll
    for (int nt = 0; nt < 13; nt++) {
      int col = nt * 16 + ln15;
      int kr_ = kra[col], kc_ = kca[col];
#pragma unroll
      for (int g = 0; g < 4; g++) {
        float v = sacc[nt][g] * 0.125f + Shs[qi[g] + kr_] + Sws[qci[g] + kc_];
        if (col >= 196) v = -1e30f;
        sacc[nt][g] = v;
        rmax[g] = fmaxf(rmax[g], v);
      }
    }
#pragma unroll
    for (int off = 1; off < 16; off <<= 1)
#pragma unroll
      for (int g = 0; g < 4; g++)
        rmax[g] = fmaxf(rmax[g], __shfl_xor(rmax[g], off, 16));
    float rsum[4] = {0.f, 0.f, 0.f, 0.f};
#pragma unroll
    for (int nt = 0; nt < 13; nt++) {
      int col = nt * 16 + ln15;
#pragma unroll
      for (int g = 0; g < 4; g++) {
        float p = (col >= 196) ? 0.f : __expf(sacc[nt][g] - rmax[g]);
        sacc[nt][g] = p;
        rsum[g] += p;
      }
    }
#pragma unroll
    for (int off = 1; off < 16; off <<= 1)
#pragma unroll
      for (int g = 0; g < 4; g++) rsum[g] += __shfl_xor(rsum[g], off, 16);
    float rinv[4];
#pragma unroll
    for (int g = 0; g < 4; g++) rinv[g] = 1.0f / rsum[g];

    // ---- write P strip (row-major [16][232] bf16, A-layout source for PV) ----
#pragma unroll
    for (int nt = 0; nt < 13; nt++) {
      int col = nt * 16 + ln15;
#pragma unroll
      for (int g = 0; g < 4; g++)
        strip[(quad * 4 + g) * 232 + col] = f2bf(sacc[nt][g] * rinv[g]);
    }

    // ---- O = P V  (K padded to 224; strip/Vt zeros beyond 196) ----
    f32x4 oacc[4];
#pragma unroll
    for (int c4 = 0; c4 < 4; c4++) oacc[c4] = fz;
#pragma unroll
    for (int ks = 0; ks < 7; ks++) {
      bf16x8 ap = ld8(strip + ln15 * 232 + ks * 32 + quad * 8);
#pragma unroll
      for (int c4 = 0; c4 < 4; c4++) {
        bf16x8 bvv = ld8(&Vt[c4 * 16 + ln15][ks * 32 + quad * 8]);
        oacc[c4] = __builtin_amdgcn_mfma_f32_16x16x32_bf16(ap, bvv, oacc[c4], 0, 0, 0);
      }
    }
    // ---- store (C-layout: col=lane&15 channel, row=quad*4+g token) ----
#pragma unroll
    for (int c4 = 0; c4 < 4; c4++)
#pragma unroll
      for (int g = 0; g < 4; g++) {
        int row = r0 + g;
        if (row < 196)
          attnout[((size_t)win * 196 + row) * 768 + head * 64 + c4 * 16 + ln15] =
              f2bf(oacc[c4][g]);
      }
  }
}

// ---------------------------------------------------------------------------
// Launch. Workspace layout (bytes):
//   [0, 60211200)              region A: xw bf16 [39200][768] -> attnout -> ln2
//   [60211200, 261537792)      region B: qkv bf16 [39200][2304] -> mlp1 [32768][3072]
//   [261537792, ...)           transposed weights bf16 + ShSw tables (~14.2 MB)
// Peak ws use ~276 MB.
// ---------------------------------------------------------------------------
extern "C" void kernel_launch(void* const* d_in, const int* in_sizes, int n_in,
                              void* d_out, int out_size, void* d_ws,
                              size_t ws_size, hipStream_t stream) {
  const float* x = (const float*)d_in[0];
  const int* q_idx = (const int*)d_in[1];
  const int* k_idx = (const int*)d_in[2];
  const float* ln1w = (const float*)d_in[3];
  const float* ln1b = (const float*)d_in[4];
  const float* ln2w = (const float*)d_in[5];
  const float* ln2b = (const float*)d_in[6];
  const float* qkvw = (const float*)d_in[7];
  const float* qkvb = (const float*)d_in[8];
  const float* projw = (const float*)d_in[9];
  const float* projb = (const float*)d_in[10];
  const float* relh = (const float*)d_in[11];
  const float* relw = (const float*)d_in[12];
  const float* w1 = (const float*)d_in[13];
  const float* b1 = (const float*)d_in[14];
  const float* w2 = (const float*)d_in[15];
  const float* b2 = (const float*)d_in[16];
  float* out = (float*)d_out;

  char* ws = (char*)d_ws;
  unsigned short* xw = (unsigned short*)ws;  // region A
  const size_t offA = 60211200;              // 39200*768*2
  unsigned short* qkv = (unsigned short*)(ws + offA);  // region B
  const size_t offB = offA + 201326592;      // max(qkv, mlp1)
  unsigned short* qkvwt = (unsigned short*)(ws + offB);
  unsigned short* projwt = qkvwt + 2304 * 768;
  unsigned short* w1t = projwt + 768 * 768;
  unsigned short* w2t = w1t + 3072 * 768;
  float* shsw = (float*)(w2t + 768 * 3072);

  unsigned short* attnout = xw;  // region A reuse (xw dead after qkv GEMM)
  unsigned short* ln2buf = xw;   // region A reuse (attnout dead after proj)
  unsigned short* mlp1 = qkv;    // region B reuse (qkv dead after attention)

  // zero xw so spatially-padded window tokens are zero feature vectors
  hipMemsetAsync(xw, 0, (size_t)39200 * 768 * 2, stream);

  dim3 tb(32, 8);
  transpose_w<<<dim3(2304 / 32, 768 / 32), tb, 0, stream>>>(qkvw, qkvwt, 768, 2304);
  transpose_w<<<dim3(768 / 32, 768 / 32), tb, 0, stream>>>(projw, projwt, 768, 768);
  transpose_w<<<dim3(3072 / 32, 768 / 32), tb, 0, stream>>>(w1, w1t, 768, 3072);
  transpose_w<<<dim3(768 / 32, 3072 / 32), tb, 0, stream>>>(w2, w2t, 3072, 768);
  shsw_kernel<<<1, 256, 0, stream>>>(relh, relw, shsw);

  // LN1 + window partition -> bf16
  ln_kernel<<<32768, 192, 0, stream>>>(x, ln1w, ln1b, xw, 1);

  // qkv = xw @ qkv_w + b   [39200,768]x[768,2304]
  gemm_bt<0><<<dim3(18, 307), 256, 0, stream>>>(xw, qkvwt, qkvb, 39200, 2304,
                                                768, qkv, nullptr, nullptr);
  // fused windowed attention
  attn_kernel<<<2400, 256, 0, stream>>>(qkv, q_idx, k_idx, shsw, attnout);

  // proj + residual + unpartition -> d_out (fp32 x_mid)
  gemm_bt<1><<<dim3(6, 307), 256, 0, stream>>>(attnout, projwt, projb, 39200,
                                               768, 768, nullptr, out, x);
  // LN2 -> bf16
  ln_kernel<<<32768, 192, 0, stream>>>(out, ln2w, ln2b, ln2buf, 0);

  // mlp1 = gelu(ln2 @ w1 + b1)   [32768,768]x[768,3072]
  gemm_bt<2><<<dim3(24, 256), 256, 0, stream>>>(ln2buf, w1t, b1, 32768, 3072,
                                                768, mlp1, nullptr, nullptr);
  // d_out += mlp1 @ w2 + b2      [32768,3072]x[3072,768]
  gemm_bt<3><<<dim3(6, 256), 256, 0, stream>>>(mlp1, w2t, b2, 32768, 768, 3072,
                                               nullptr, out, nullptr);
  (void)in_sizes; (void)n_in; (void)out_size; (void)ws_size;
}